// Round 4
// baseline (504.516 us; speedup 1.0000x reference)
//
#include <hip/hip_runtime.h>
#include <stdint.h>

typedef unsigned short u16;
typedef float f32x4 __attribute__((ext_vector_type(4)));
typedef short bf16x8 __attribute__((ext_vector_type(8)));

#define MFMA(a,b,c) __builtin_amdgcn_mfma_f32_16x16x32_bf16((a),(b),(c),0,0,0)

__device__ __forceinline__ u16 f2b(float f){
  union { float f; unsigned u; } x; x.f = f;
  unsigned r = x.u + 0x7FFFu + ((x.u >> 16) & 1u);   // RNE
  return (u16)(r >> 16);
}
__device__ __forceinline__ float b2f(u16 b){
  union { unsigned u; float f; } x; x.u = ((unsigned)b) << 16;
  return x.f;
}
__device__ __forceinline__ float ldin(const void* p, long long i, int isbf){
  return isbf ? b2f(((const u16*)p)[i]) : ((const float*)p)[i];
}
typedef const __attribute__((address_space(1))) void gas_t;
typedef __attribute__((address_space(3))) void sas_t;
__device__ __forceinline__ void gl16(const void* g, void* l){
  __builtin_amdgcn_global_load_lds((gas_t*)g, (sas_t*)l, 16, 0, 0);
}
__device__ __forceinline__ float sigm(float x){ return 1.f/(1.f + __expf(-x)); }
__device__ __forceinline__ float tanh_f(float x){
  float e2 = __expf(-2.f*fabsf(x));
  float t = (1.f - e2)/(1.f + e2);
  return copysignf(t, x);
}

// N=4 I=64 C=256 G=8 Cg=32 K=9 H=W=48 HW=2304 Hd=Wd=40 D=1600 pad=4 (56x56 padded)
static constexpr size_t OFF_FLAG = 0;
static constexpr size_t OFF_WB = 256;                     // conv w bf16 [g][81][224][64]
static constexpr size_t SZ_WB  = (size_t)8*81*224*64*2;
static constexpr size_t OFF_WP = OFF_WB + SZ_WB;          // proj w bf16 [256][320]
static constexpr size_t SZ_WP  = (size_t)256*320*2;
static constexpr size_t OFF_UT = OFF_WP + SZ_WP;          // [n][2304][320] bf16
static constexpr size_t SZ_UT  = (size_t)4*2304*320*2;
static constexpr size_t OFF_XH = OFF_UT + SZ_UT;          // [n][g][56][56][64] bf16
static constexpr size_t SZ_XH  = (size_t)32*3136*64*2;
static constexpr size_t OFF_QB = OFF_XH + SZ_XH;          // [n][g][32][2304] bf16
static constexpr size_t SZ_QB  = (size_t)32*32*2304*2;
static constexpr size_t OFF_KT = OFF_QB + SZ_QB;          // [n][g][1600][32] bf16 (K transposed!)
static constexpr size_t SZ_KT  = (size_t)32*1600*32*2;
static constexpr size_t OFF_VB = OFF_KT + SZ_KT;          // [n][g][32][1600] bf16
static constexpr size_t OFF_GP = OFF_VB + SZ_KT;          // [n][g][4][32][2304] bf16 gate pre-acts
static constexpr size_t SZ_GP  = (size_t)32*4*32*2304*2;
static constexpr size_t OFF_AB = OFF_GP + SZ_GP;          // [n][g][32][2304] f32 attention out
static constexpr size_t SZ_AB  = (size_t)32*32*2304*4;

// ---------------- probe: detect bf16 vs fp32 inputs ----------------
__global__ void k_probe(const unsigned* u, int* flag){
  int t = threadIdx.x;
  unsigned v = u[t];
  unsigned e = (v >> 7) & 0xFF;
  int is = (e >= 0x70 && e <= 0x88) ? 1 : 0;
  unsigned long long m = __ballot(is);
  __shared__ int cnt[4];
  if ((t & 63) == 0) cnt[t >> 6] = __popcll(m);
  __syncthreads();
  if (t == 0) *flag = (cnt[0]+cnt[1]+cnt[2]+cnt[3] >= 128) ? 1 : 0;
}

// ---------------- pack conv weights ----------------
__global__ void k_packw(const void* Wq, const void* Wk, const void* Wv,
                        const void* Wi, const void* Wf, const void* Wg,
                        const void* Wo, u16* WB, const int* flag){
  int b = blockIdx.x; int ocl = b & 31; int tt = (b >> 5) % 7; int g = b / 224;
  int tid = threadIdx.x; int isbf = *flag;
  const void* srcs[7] = {Wq, Wk, Wv, Wi, Wf, Wg, Wo};
  const void* src = srcs[tt];
  __shared__ float s[5184];
  long long base = (long long)(g*32 + ocl) * 5184;
  for (int i = tid; i < 5184; i += 256) s[i] = ldin(src, base + i, isbf);
  __syncthreads();
  int oc = tt*32 + ocl;
  for (int i = tid; i < 5184; i += 256){
    int kk = i >> 6, ci = i & 63;
    int pos = ((((ci >> 3) ^ (ocl & 7)) << 3) | (ci & 7));
    WB[((size_t)(g*81 + kk)*224 + oc)*64 + pos] = f2b(s[ci*81 + kk]);
  }
}

// ---------------- pack proj weights ----------------
__global__ void k_packp(const void* Wx, const void* Wxg, u16* Wp, const int* flag){
  int el = blockIdx.x*256 + threadIdx.x;
  int isbf = *flag;
  if (el >= 81920) return;
  int oc = el / 320, k = el % 320;
  float v = (k < 64) ? ldin(Wx, (long long)oc*64 + k, isbf)
                     : ldin(Wxg, (long long)oc*256 + (k - 64), isbf);
  int win = k >> 6, pos = k & 63;
  int dpos = (win << 6) | ((((pos >> 3) ^ (oc & 7)) << 3)) | (pos & 7);
  Wp[(size_t)oc*320 + dpos] = f2b(v);
}

// ---------------- build U_T + h-part of xh_pad ----------------
__global__ void k_ut(const void* inp, const void* h, u16* UT, u16* xh, const int* flag){
  int b = blockIdx.x; int qb = b % 18; int s = (b / 18) % 5; int n = b / 90;
  int tid = threadIdx.x; int isbf = *flag;
  __shared__ float sb[64][129];
  const void* src = (s == 0) ? inp : h;
  long long base = (s == 0) ? (long long)n*64*2304 : ((long long)n*256 + (s-1)*64)*2304;
  for (int i = 0; i < 32; i++){
    int el = tid + i*256; int r = el >> 7, q = el & 127;
    sb[r][q] = ldin(src, base + (long long)r*2304 + qb*128 + q, isbf);
  }
  __syncthreads();
  int koff = (s == 0) ? 0 : 64 + (s-1)*64;
  for (int i = 0; i < 4; i++){
    int chunk = tid + i*256;
    int q = chunk >> 3, c8 = chunk & 7;
    bf16x8 v;
    #pragma unroll
    for (int j = 0; j < 8; j++) v[j] = (short)f2b(sb[c8*8 + j][q]);
    *(bf16x8*)&UT[((size_t)(n*2304 + qb*128 + q))*320 + koff + c8*8] = v;
  }
  if (s > 0){
    for (int i = 0; i < 4; i++){
      int chunk = tid + i*256;
      int q = chunk >> 3, gg = (chunk >> 2) & 1, seg = chunk & 3;
      int g = (s-1)*2 + gg;
      int qg = qb*128 + q; int y = qg / 48, x = qg - y*48;
      bf16x8 v;
      #pragma unroll
      for (int j = 0; j < 8; j++) v[j] = (short)f2b(sb[gg*32 + seg*8 + j][q]);
      *(bf16x8*)&xh[(((size_t)((n*8+g)*56 + y+4))*56 + (x+4))*64 + 32 + seg*8] = v;
    }
  }
}

// ---------------- proj GEMM ----------------
__global__ __launch_bounds__(384) void k_proj(const u16* Wp, const u16* UT, u16* xh){
  int b = blockIdx.x; int qblk = b & 15; int n = b >> 4;
  int tid = threadIdx.x; int lane = tid & 63; int wid = tid >> 6;
  int wm = wid % 3, wn = wid / 3;
  int quad = lane >> 4, m16 = lane & 15;
  __shared__ __align__(16) u16 lA[144*64];
  __shared__ __align__(16) u16 lB[256*64];
  size_t abase[3];
  #pragma unroll
  for (int r = 0; r < 3; r++){
    int chunk = tid + r*384; int j = chunk >> 3, cs = chunk & 7;
    int cc = cs ^ (j & 7);
    abase[r] = ((size_t)(n*2304 + qblk*144 + j))*320 + cc*8;
  }
  f32x4 acc[3][8];
  #pragma unroll
  for (int a = 0; a < 3; a++)
    #pragma unroll
    for (int c = 0; c < 8; c++) acc[a][c] = (f32x4){0.f,0.f,0.f,0.f};

  for (int kb = 0; kb < 5; kb++){
    __syncthreads();
    #pragma unroll
    for (int r = 0; r < 3; r++)
      gl16(&UT[abase[r] + kb*64], &lA[(tid + r*384)*8]);
    #pragma unroll
    for (int r = 0; r < 6; r++){
      int chunk = tid + r*384;
      if (chunk < 2048)
        gl16(&Wp[(size_t)(chunk >> 3)*320 + kb*64 + (chunk & 7)*8], &lB[chunk*8]);
    }
    __syncthreads();
    #pragma unroll
    for (int ks = 0; ks < 2; ks++){
      int sw = ((ks*4 + quad) ^ (lane & 7))*8;
      bf16x8 af[3], bfr[8];
      #pragma unroll
      for (int mt = 0; mt < 3; mt++)
        af[mt] = *(const bf16x8*)&lA[(wm*48 + mt*16 + m16)*64 + sw];
      #pragma unroll
      for (int nt = 0; nt < 8; nt++)
        bfr[nt] = *(const bf16x8*)&lB[(wn*128 + nt*16 + m16)*64 + sw];
      #pragma unroll
      for (int mt = 0; mt < 3; mt++)
        #pragma unroll
        for (int nt = 0; nt < 8; nt++)
          acc[mt][nt] = MFMA(af[mt], bfr[nt], acc[mt][nt]);
    }
  }
  #pragma unroll
  for (int mt = 0; mt < 3; mt++)
    #pragma unroll
    for (int nt = 0; nt < 8; nt++)
      #pragma unroll
      for (int r = 0; r < 4; r++){
        int q = qblk*144 + wm*48 + mt*16 + quad*4 + r;
        int oc = wn*128 + nt*16 + m16;
        int y = q / 48, x = q - y*48;
        int g = oc >> 5, ci = oc & 31;
        xh[(((size_t)((n*8+g)*56 + y+4))*56 + (x+4))*64 + ci] = f2b(acc[mt][nt][r]);
      }
}

// ---------------- fused 7-conv implicit GEMM, 2 blocks/CU ----------------
// grid 512 = n(4) x g(8) x qb(16); 384 thr = 6 waves (wm 2 x 112oc, wn 3 x 48sp)
// tile 224 oc x 144 sp (3 rows). LDS 64KB: A single 28KB + B dbuf 2x18KB.
// barrier1: buffers ready; af -> regs; barrier2: A consumable; prefetch; MFMA.
__global__ __launch_bounds__(384, 3) void k_conv(const u16* WB, const u16* xh,
                                                 u16* Qb, u16* Kt, u16* Vb, u16* Gp){
  extern __shared__ __align__(16) u16 sm[];   // A: [0,14336); B: [14336 + buf*9216)
  int b = blockIdx.x; int qb = b & 15; int gg = (b >> 4) & 7; int n = b >> 7;
  int tid = threadIdx.x; int lane = tid & 63; int wid = tid >> 6;
  int wm = wid & 1, wn = wid >> 1;        // wm 0..1, wn 0..2
  int quad = lane >> 4, m16 = lane & 15;
  int y0 = qb*3;
  const u16* WBg = WB + (size_t)gg*81*14336;
  const u16* xg  = xh + (size_t)((n*8+gg)*3136)*64;
  int bsrc[3];
  #pragma unroll
  for (int r = 0; r < 3; r++){
    int c = tid + r*384;                  // 1152 B-chunks
    int dy = c / 384, rem = c % 384;
    int col = rem >> 3, cs = rem & 7;
    bsrc[r] = ((y0+dy)*56 + col)*64 + (cs ^ (col & 7))*8;
  }
  f32x4 acc[7][3];
  #pragma unroll
  for (int a = 0; a < 7; a++)
    #pragma unroll
    for (int c = 0; c < 3; c++) acc[a][c] = (f32x4){0.f,0.f,0.f,0.f};

  // prologue: A(0) + B(0)->buf0
  #pragma unroll
  for (int r = 0; r < 4; r++){
    int c = tid + r*384;
    gl16(&WBg[c*8], &sm[c*8]);
  }
  if (tid < 256){ int c = 1536 + tid; gl16(&WBg[c*8], &sm[c*8]); }
  #pragma unroll
  for (int r = 0; r < 3; r++)
    gl16(&xg[bsrc[r]], &sm[14336 + (tid + r*384)*8]);

  int ky = 0, kx = 0;
  for (int kk = 0; kk < 81; kk++){
    __syncthreads();                      // barrier1: A(kk), B(kk) staged
    bf16x8 af0[7], af1[7];
    #pragma unroll
    for (int mt = 0; mt < 7; mt++){
      int rr = wm*112 + mt*16 + m16;
      af0[mt] = *(const bf16x8*)&sm[rr*64 + ((quad     ^ (rr&7))*8)];
      af1[mt] = *(const bf16x8*)&sm[rr*64 + (((4+quad) ^ (rr&7))*8)];
    }
    __syncthreads();                      // barrier2: all waves hold A in regs
    if (kk < 80){
      int kx1 = kx + 1, ky1 = ky;
      if (kx1 == 9){ kx1 = 0; ky1++; }
      const u16* As = WBg + (size_t)(kk+1)*14336;
      #pragma unroll
      for (int r = 0; r < 4; r++){
        int c = tid + r*384;
        gl16(&As[c*8], &sm[c*8]);
      }
      if (tid < 256){ int c = 1536 + tid; gl16(&As[c*8], &sm[c*8]); }
      int koff = (ky1*56 + kx1)*64;
      u16* Bn = &sm[14336 + (size_t)((kk+1)&1)*9216];
      #pragma unroll
      for (int r = 0; r < 3; r++)
        gl16(&xg[bsrc[r] + koff], &Bn[(tid + r*384)*8]);
    }
    const u16* B = &sm[14336 + (size_t)(kk&1)*9216];
    bf16x8 bfr[3];
    #pragma unroll
    for (int nt = 0; nt < 3; nt++){
      int sp = wn*48 + nt*16 + m16;
      bfr[nt] = *(const bf16x8*)&B[sp*64 + ((quad ^ (sp&7))*8)];
    }
    #pragma unroll
    for (int mt = 0; mt < 7; mt++)
      #pragma unroll
      for (int nt = 0; nt < 3; nt++)
        acc[mt][nt] = MFMA(af0[mt], bfr[nt], acc[mt][nt]);
    #pragma unroll
    for (int nt = 0; nt < 3; nt++){
      int sp = wn*48 + nt*16 + m16;
      bfr[nt] = *(const bf16x8*)&B[sp*64 + (((4+quad) ^ (sp&7))*8)];
    }
    #pragma unroll
    for (int mt = 0; mt < 7; mt++)
      #pragma unroll
      for (int nt = 0; nt < 3; nt++)
        acc[mt][nt] = MFMA(af1[mt], bfr[nt], acc[mt][nt]);
    kx++; if (kx == 9){ kx = 0; ky++; }
  }
  // epilogue: row = oc, col = spatial
  int y = y0 + wn;
  size_t ng = (size_t)(n*8 + gg);
  #pragma unroll
  for (int mt = 0; mt < 7; mt++){
    int ocb = wm*112 + mt*16 + quad*4;
    #pragma unroll
    for (int nt = 0; nt < 3; nt++){
      int x = nt*16 + m16;
      int q = y*48 + x;
      #pragma unroll
      for (int r = 0; r < 4; r++){
        float v = acc[mt][nt][r];
        int oc = ocb + r;
        int t7 = oc >> 5, ocl = oc & 31;
        if (t7 == 0){
          Qb[(ng*32 + ocl)*2304 + q] = f2b(v);
        } else if (t7 <= 2){
          if ((unsigned)(y-4) < 40u && (unsigned)(x-4) < 40u){
            int d = (y-4)*40 + (x-4);
            if (t7 == 1) Kt[(ng*1600 + d)*32 + ocl] = f2b(v);   // transposed [d][c]
            else         Vb[(ng*32 + ocl)*1600 + d] = f2b(v);
          }
        } else {
          Gp[((ng*4 + (t7-3))*32 + ocl)*2304 + q] = f2b(v);
        }
      }
    }
  }
}

// ---------------- attention: single-pass online softmax ----------------
// grid 576 = n(4) x g(8) x qb(18); 256 thr = 4 waves, 32 q each; 25 d-tiles of 64
__global__ __launch_bounds__(256) void k_attn(const u16* Qb, const u16* Kt, const u16* Vb,
                                              float* Ab, const void* tau, const int* flag){
  int b = blockIdx.x; int qb = b % 18; int g = (b / 18) & 7; int n = b / 144;
  int tid = threadIdx.x; int lane = tid & 63; int wid = tid >> 6;
  int quad = lane >> 4, m16 = lane & 15;
  int isbf = *flag;
  __shared__ __align__(16) u16 sQ[128*40];     // [q][c] stride 40
  __shared__ __align__(16) u16 sK[2][2048];    // [d64][c32], src-XOR chunks
  __shared__ __align__(16) u16 sV[2][2048];    // [c32][d64], src-XOR chunks
  __shared__ __align__(16) u16 sP[4][32*72];   // per-wave [q][d] stride 72
  __shared__ float sAl[128];
  __shared__ float sL[128];
  size_t ng = (size_t)(n*8 + g);
  const u16* Qg  = Qb + ng*32*2304;
  const u16* Ktg = Kt + ng*1600*32;
  const u16* Vg  = Vb + ng*32*1600;
  float tauv = ldin(tau, g, isbf);
  for (int i = 0; i < 16; i++){
    int el = tid + i*256; int c = el >> 7, q = el & 127;
    sQ[q*40 + c] = Qg[(size_t)c*2304 + qb*128 + q];
  }
  int kd = tid >> 2, kc = ((tid & 3) ^ (kd & 3))*8;     // K-tile staging coords
  int vc = tid >> 3, vd = ((tid & 7) ^ (vc & 7))*8;     // V-tile staging coords
  gl16(&Ktg[(size_t)kd*32 + kc], &sK[0][tid*8]);
  gl16(&Vg[(size_t)vc*1600 + vd], &sV[0][tid*8]);
  __syncthreads();
  bf16x8 aq[2];
  #pragma unroll
  for (int mt = 0; mt < 2; mt++)
    aq[mt] = *(const bf16x8*)&sQ[(wid*32 + mt*16 + m16)*40 + quad*8];

  float mrun[2][4], lrun[2][4];
  f32x4 oacc[2][2];
  #pragma unroll
  for (int a = 0; a < 2; a++)
    #pragma unroll
    for (int r = 0; r < 4; r++){ mrun[a][r] = -3e38f; lrun[a][r] = 0.f; }
  #pragma unroll
  for (int a = 0; a < 2; a++)
    #pragma unroll
    for (int c = 0; c < 2; c++) oacc[a][c] = (f32x4){0.f,0.f,0.f,0.f};
  u16* myP = sP[wid];

  for (int dt = 0; dt < 25; dt++){
    __syncthreads();                       // tiles[dt&1] staged
    const u16* K = sK[dt&1];
    const u16* V = sV[dt&1];
    if (dt < 24){
      gl16(&Ktg[(size_t)((dt+1)*64 + kd)*32 + kc], &sK[1-(dt&1)][tid*8]);
      gl16(&Vg[(size_t)vc*1600 + (dt+1)*64 + vd], &sV[1-(dt&1)][tid*8]);
    }
    // S = Q^T K  (rows q, cols d)
    f32x4 sacc[2][4];
    #pragma unroll
    for (int a = 0; a < 2; a++)
      #pragma unroll
      for (int c = 0; c < 4; c++) sacc[a][c] = (f32x4){0.f,0.f,0.f,0.f};
    #pragma unroll
    for (int nt = 0; nt < 4; nt++){
      int d = nt*16 + m16;
      bf16x8 bk = *(const bf16x8*)&K[d*32 + ((quad ^ (d&3))*8)];
      #pragma unroll
      for (int mt = 0; mt < 2; mt++)
        sacc[mt][nt] = MFMA(aq[mt], bk, sacc[mt][nt]);
    }
    // online max + alpha
    float alpha[2][4];
    #pragma unroll
    for (int mt = 0; mt < 2; mt++)
      #pragma unroll
      for (int r = 0; r < 4; r++){
        float v = fmaxf(fmaxf(sacc[mt][0][r], sacc[mt][1][r]),
                        fmaxf(sacc[mt][2][r], sacc[mt][3][r])) * tauv;
        v = fmaxf(v, __shfl_xor(v, 1));
        v = fmaxf(v, __shfl_xor(v, 2));
        v = fmaxf(v, __shfl_xor(v, 4));
        v = fmaxf(v, __shfl_xor(v, 8));
        float mnew = fmaxf(mrun[mt][r], v);
        alpha[mt][r] = __expf(mrun[mt][r] - mnew);
        mrun[mt][r] = mnew;
      }
    // P = exp(S*tau - m), write to LDS, row-sum
    float ps[2][4] = {{0.f,0.f,0.f,0.f},{0.f,0.f,0.f,0.f}};
    #pragma unroll
    for (int mt = 0; mt < 2; mt++)
      #pragma unroll
      for (int nt = 0; nt < 4; nt++)
        #pragma unroll
        for (int r = 0; r < 4; r++){
          float p = __expf(sacc[mt][nt][r]*tauv - mrun[mt][r]);
          ps[mt][r] += p;
          myP[(mt*16 + quad*4 + r)*72 + nt*16 + m16] = f2b(p);
        }
    #pragma unroll
    for (int mt = 0; mt < 2; mt++)
      #pragma unroll
      for (int r = 0; r < 4; r++){
        float v = ps[mt][r];
        v += __shfl_xor(v, 1);
        v += __shfl_xor(v, 2);
        v += __shfl_xor(v, 4);
        v += __shfl_xor(v, 8);
        lrun[mt][r] = lrun[mt][r]*alpha[mt][r] + v;
      }
    if (m16 == 0){
      #pragma unroll
      for (int mt = 0; mt < 2; mt++)
        #pragma unroll
        for (int r = 0; r < 4; r++)
          sAl[wid*32 + mt*16 + quad*4 + r] = alpha[mt][r];
    }
    __syncthreads();                       // P + alpha visible
    float a0 = sAl[wid*32 + m16];
    float a1 = sAl[wid*32 + 16 + m16];
    #pragma unroll
    for (int mtc = 0; mtc < 2; mtc++){
      oacc[mtc][0] *= a0;
      oacc[mtc][1] *= a1;
    }
    #pragma unroll
    for (int ks = 0; ks < 2; ks++){
      bf16x8 av[2], bp[2];
      #pragma unroll
      for (int mtc = 0; mtc < 2; mtc++){
        int c = mtc*16 + m16;
        av[mtc] = *(const bf16x8*)&V[c*64 + (((ks*4+quad) ^ (c&7))*8)];
      }
      #pragma unroll
      for (int ntq = 0; ntq < 2; ntq++)
        bp[ntq] = *(const bf16x8*)&myP[(ntq*16 + m16)*72 + ks*32 + quad*8];
      #pragma unroll
      for (int mtc = 0; mtc < 2; mtc++)
        #pragma unroll
        for (int ntq = 0; ntq < 2; ntq++)
          oacc[mtc][ntq] = MFMA(av[mtc], bp[ntq], oacc[mtc][ntq]);
    }
  }
  if (m16 == 0){
    #pragma unroll
    for (int mt = 0; mt < 2; mt++)
      #pragma unroll
      for (int r = 0; r < 4; r++)
        sL[wid*32 + mt*16 + quad*4 + r] = lrun[mt][r];
  }
  __syncthreads();
  #pragma unroll
  for (int mtc = 0; mtc < 2; mtc++)
    #pragma unroll
    for (int ntq = 0; ntq < 2; ntq++){
      float linv = 1.0f / sL[wid*32 + ntq*16 + m16];
      int q = qb*128 + wid*32 + ntq*16 + m16;
      #pragma unroll
      for (int r = 0; r < 4; r++){
        int c = mtc*16 + quad*4 + r;
        Ab[(ng*32 + c)*2304 + q] = oacc[mtc][ntq][r] * linv;
      }
    }
}

// ---------------- gates + LSTM pointwise ----------------
__global__ __launch_bounds__(256) void k_final(const float* Ab, const u16* Gp,
    const void* Wai, const void* Waf, const void* Wag, const void* Wao,
    const void* bi, const void* bff, const void* bg, const void* bo,
    const void* cprev, void* out, const int* flag){
  int b = blockIdx.x; int qb = b % 18; int g = (b / 18) & 7; int n = b / 144;
  int tid = threadIdx.x; int isbf = *flag;
  __shared__ float sa[32][129];
  __shared__ float sw[4][32][33];
  __shared__ float sbias[4][32];
  size_t ng = (size_t)(n*8 + g);
  for (int i = 0; i < 16; i++){
    int el = tid + i*256; int c = el >> 7, q = el & 127;
    sa[c][q] = Ab[(ng*32 + c)*2304 + qb*128 + q];
  }
  const void* Ws[4] = {Wai, Waf, Wag, Wao};
  #pragma unroll
  for (int k = 0; k < 4; k++)
    for (int i = tid; i < 1024; i += 256){
      int oc = i >> 5, ci = i & 31;
      sw[k][oc][ci] = ldin(Ws[k], (long long)(g*32 + oc)*32 + ci, isbf);
    }
  if (tid < 128){
    int k = tid >> 5, oc = tid & 31;
    const void* Bs[4] = {bi, bff, bg, bo};
    sbias[k][oc] = ldin(Bs[k], g*32 + oc, isbf);
  }
  __syncthreads();
  int oc = tid >> 3, q8 = tid & 7;
  for (int it = 0; it < 16; it++){
    int q = it*8 + q8;
    int qg = qb*128 + q;
    float a0 = sbias[0][oc], a1 = sbias[1][oc], a2 = sbias[2][oc], a3 = sbias[3][oc];
    #pragma unroll
    for (int ci = 0; ci < 32; ci++){
      float av = sa[ci][q];
      a0 += sw[0][oc][ci]*av;
      a1 += sw[1][oc][ci]*av;
      a2 += sw[2][oc][ci]*av;
      a3 += sw[3][oc][ci]*av;
    }
    a0 += b2f(Gp[((ng*4 + 0)*32 + oc)*2304 + qg]);
    a1 += b2f(Gp[((ng*4 + 1)*32 + oc)*2304 + qg]);
    a2 += b2f(Gp[((ng*4 + 2)*32 + oc)*2304 + qg]);
    a3 += b2f(Gp[((ng*4 + 3)*32 + oc)*2304 + qg]);
    float gi = sigm(a0), gf = sigm(a1), gv = tanh_f(a2), go = sigm(a3);
    long long cidx = ((long long)n*256 + g*32 + oc)*2304 + qg;
    float cp = ldin(cprev, cidx, isbf);
    float cn = gf*cp + gi*gv;
    float hv = go * tanh_f(cn);
    if (isbf) ((u16*)out)[cidx] = f2b(hv);
    else      ((float*)out)[cidx] = hv;
  }
}

extern "C" void kernel_launch(void* const* d_in, const int* in_sizes, int n_in,
                              void* d_out, int out_size, void* d_ws, size_t ws_size,
                              hipStream_t stream){
  const void* inp  = d_in[0];
  const void* h    = d_in[1];
  const void* cpv  = d_in[2];
  const void* Wx   = d_in[3];
  const void* Wxg  = d_in[4];
  const void* tau  = d_in[5];
  const void* Wq   = d_in[6];
  const void* Wk   = d_in[7];
  const void* Wv   = d_in[8];
  const void* Wai  = d_in[9];  const void* Wxi = d_in[10]; const void* bi = d_in[11];
  const void* Waf  = d_in[12]; const void* Wxf = d_in[13]; const void* bff = d_in[14];
  const void* Wag  = d_in[15]; const void* Wxg2 = d_in[16]; const void* bg = d_in[17];
  const void* Wao  = d_in[18]; const void* Wxo = d_in[19]; const void* bo = d_in[20];

  char* ws = (char*)d_ws;
  int*  flag = (int*)(ws + OFF_FLAG);
  u16*  WB = (u16*)(ws + OFF_WB);
  u16*  Wp = (u16*)(ws + OFF_WP);
  u16*  UT = (u16*)(ws + OFF_UT);
  u16*  XH = (u16*)(ws + OFF_XH);
  u16*  Qb = (u16*)(ws + OFF_QB);
  u16*  Kt = (u16*)(ws + OFF_KT);
  u16*  Vb = (u16*)(ws + OFF_VB);
  u16*  Gp = (u16*)(ws + OFF_GP);
  float* Ab = (float*)(ws + OFF_AB);

  (void)hipFuncSetAttribute(reinterpret_cast<const void*>(k_conv),
                            hipFuncAttributeMaxDynamicSharedMemorySize, 65536);

  (void)hipMemsetAsync(XH, 0, SZ_XH, stream);
  k_probe<<<1, 256, 0, stream>>>((const unsigned*)inp, flag);
  k_packw<<<1792, 256, 0, stream>>>(Wq, Wk, Wv, Wxi, Wxf, Wxg2, Wxo, WB, flag);
  k_packp<<<320, 256, 0, stream>>>(Wx, Wxg, Wp, flag);
  k_ut<<<360, 256, 0, stream>>>(inp, h, UT, XH, flag);
  k_proj<<<64, 384, 0, stream>>>(Wp, UT, XH);
  k_conv<<<512, 384, 65536, stream>>>(WB, XH, Qb, Kt, Vb, Gp);
  k_attn<<<576, 256, 0, stream>>>(Qb, Kt, Vb, Ab, tau, flag);
  k_final<<<576, 256, 0, stream>>>(Ab, Gp, Wai, Waf, Wag, Wao,
                                   bi, bff, bg, bo, cpv, d_out, flag);
}

// Round 5
// 461.442 us; speedup vs baseline: 1.0933x; 1.0933x over previous
//
#include <hip/hip_runtime.h>
#include <stdint.h>

typedef unsigned short u16;
typedef float f32x4 __attribute__((ext_vector_type(4)));
typedef float f32x4v __attribute__((ext_vector_type(4)));
typedef short bf16x8 __attribute__((ext_vector_type(8)));

#define MFMA(a,b,c) __builtin_amdgcn_mfma_f32_16x16x32_bf16((a),(b),(c),0,0,0)

__device__ __forceinline__ u16 f2b(float f){
  union { float f; unsigned u; } x; x.f = f;
  unsigned r = x.u + 0x7FFFu + ((x.u >> 16) & 1u);   // RNE
  return (u16)(r >> 16);
}
__device__ __forceinline__ float b2f(u16 b){
  union { unsigned u; float f; } x; x.u = ((unsigned)b) << 16;
  return x.f;
}
__device__ __forceinline__ float ldin(const void* p, long long i, int isbf){
  return isbf ? b2f(((const u16*)p)[i]) : ((const float*)p)[i];
}
typedef const __attribute__((address_space(1))) void gas_t;
typedef __attribute__((address_space(3))) void sas_t;
__device__ __forceinline__ void gl16(const void* g, void* l){
  __builtin_amdgcn_global_load_lds((gas_t*)g, (sas_t*)l, 16, 0, 0);
}
__device__ __forceinline__ float sigm(float x){ return 1.f/(1.f + __expf(-x)); }
__device__ __forceinline__ float tanh_f(float x){
  float e2 = __expf(-2.f*fabsf(x));
  float t = (1.f - e2)/(1.f + e2);
  return copysignf(t, x);
}

// N=4 I=64 C=256 G=8 Cg=32 K=9 H=W=48 HW=2304 Hd=Wd=40 D=1600 pad=4 (56x56 padded)
static constexpr size_t OFF_FLAG = 0;
static constexpr size_t OFF_WB = 256;                     // conv w bf16 [g][81][224][64]
static constexpr size_t SZ_WB  = (size_t)8*81*224*64*2;
static constexpr size_t OFF_WP = OFF_WB + SZ_WB;          // proj w bf16 [256][320]
static constexpr size_t SZ_WP  = (size_t)256*320*2;
static constexpr size_t OFF_UT = OFF_WP + SZ_WP;          // [n][2304][320] bf16
static constexpr size_t SZ_UT  = (size_t)4*2304*320*2;
static constexpr size_t OFF_XH = OFF_UT + SZ_UT;          // [n][g][56][56][64] bf16
static constexpr size_t SZ_XH  = (size_t)32*3136*64*2;
static constexpr size_t OFF_QB = OFF_XH + SZ_XH;          // [n][g][32][2304] bf16
static constexpr size_t SZ_QB  = (size_t)32*32*2304*2;
static constexpr size_t OFF_KT = OFF_QB + SZ_QB;          // [n][g][1600][32] bf16 (K transposed)
static constexpr size_t SZ_KT  = (size_t)32*1600*32*2;
static constexpr size_t OFF_VB = OFF_KT + SZ_KT;          // [n][g][32][1600] bf16
static constexpr size_t OFF_GP = OFF_VB + SZ_KT;          // [n][g][4][32][2304] bf16 conv gate pre-acts
static constexpr size_t SZ_GP  = (size_t)32*4*32*2304*2;
static constexpr size_t OFF_GA = OFF_GP + SZ_GP;          // [n][g][4][32][2304] bf16 attn gate pre-acts
static constexpr size_t SZ_GA  = SZ_GP;

// ---------------- probe: detect bf16 vs fp32 inputs ----------------
__global__ void k_probe(const unsigned* u, int* flag){
  int t = threadIdx.x;
  unsigned v = u[t];
  unsigned e = (v >> 7) & 0xFF;
  int is = (e >= 0x70 && e <= 0x88) ? 1 : 0;
  unsigned long long m = __ballot(is);
  __shared__ int cnt[4];
  if ((t & 63) == 0) cnt[t >> 6] = __popcll(m);
  __syncthreads();
  if (t == 0) *flag = (cnt[0]+cnt[1]+cnt[2]+cnt[3] >= 128) ? 1 : 0;
}

// ---------------- pack conv weights ----------------
__global__ void k_packw(const void* Wq, const void* Wk, const void* Wv,
                        const void* Wi, const void* Wf, const void* Wg,
                        const void* Wo, u16* WB, const int* flag){
  int b = blockIdx.x; int ocl = b & 31; int tt = (b >> 5) % 7; int g = b / 224;
  int tid = threadIdx.x; int isbf = *flag;
  const void* srcs[7] = {Wq, Wk, Wv, Wi, Wf, Wg, Wo};
  const void* src = srcs[tt];
  __shared__ float s[5184];
  long long base = (long long)(g*32 + ocl) * 5184;
  for (int i = tid; i < 5184; i += 256) s[i] = ldin(src, base + i, isbf);
  __syncthreads();
  int oc = tt*32 + ocl;
  for (int i = tid; i < 5184; i += 256){
    int kk = i >> 6, ci = i & 63;
    int pos = ((((ci >> 3) ^ (ocl & 7)) << 3) | (ci & 7));
    WB[((size_t)(g*81 + kk)*224 + oc)*64 + pos] = f2b(s[ci*81 + kk]);
  }
}

// ---------------- pack proj weights ----------------
__global__ void k_packp(const void* Wx, const void* Wxg, u16* Wp, const int* flag){
  int el = blockIdx.x*256 + threadIdx.x;
  int isbf = *flag;
  if (el >= 81920) return;
  int oc = el / 320, k = el % 320;
  float v = (k < 64) ? ldin(Wx, (long long)oc*64 + k, isbf)
                     : ldin(Wxg, (long long)oc*256 + (k - 64), isbf);
  int win = k >> 6, pos = k & 63;
  int dpos = (win << 6) | ((((pos >> 3) ^ (oc & 7)) << 3)) | (pos & 7);
  Wp[(size_t)oc*320 + dpos] = f2b(v);
}

// ---------------- build U_T + h-part of xh_pad ----------------
__global__ void k_ut(const void* inp, const void* h, u16* UT, u16* xh, const int* flag){
  int b = blockIdx.x; int qb = b % 18; int s = (b / 18) % 5; int n = b / 90;
  int tid = threadIdx.x; int isbf = *flag;
  __shared__ float sb[64][129];
  const void* src = (s == 0) ? inp : h;
  long long base = (s == 0) ? (long long)n*64*2304 : ((long long)n*256 + (s-1)*64)*2304;
  for (int i = 0; i < 32; i++){
    int el = tid + i*256; int r = el >> 7, q = el & 127;
    sb[r][q] = ldin(src, base + (long long)r*2304 + qb*128 + q, isbf);
  }
  __syncthreads();
  int koff = (s == 0) ? 0 : 64 + (s-1)*64;
  for (int i = 0; i < 4; i++){
    int chunk = tid + i*256;
    int q = chunk >> 3, c8 = chunk & 7;
    bf16x8 v;
    #pragma unroll
    for (int j = 0; j < 8; j++) v[j] = (short)f2b(sb[c8*8 + j][q]);
    *(bf16x8*)&UT[((size_t)(n*2304 + qb*128 + q))*320 + koff + c8*8] = v;
  }
  if (s > 0){
    for (int i = 0; i < 4; i++){
      int chunk = tid + i*256;
      int q = chunk >> 3, gg = (chunk >> 2) & 1, seg = chunk & 3;
      int g = (s-1)*2 + gg;
      int qg = qb*128 + q; int y = qg / 48, x = qg - y*48;
      bf16x8 v;
      #pragma unroll
      for (int j = 0; j < 8; j++) v[j] = (short)f2b(sb[gg*32 + seg*8 + j][q]);
      *(bf16x8*)&xh[(((size_t)((n*8+g)*56 + y+4))*56 + (x+4))*64 + 32 + seg*8] = v;
    }
  }
}

// ---------------- proj GEMM ----------------
__global__ __launch_bounds__(384) void k_proj(const u16* Wp, const u16* UT, u16* xh){
  int b = blockIdx.x; int qblk = b & 15; int n = b >> 4;
  int tid = threadIdx.x; int lane = tid & 63; int wid = tid >> 6;
  int wm = wid % 3, wn = wid / 3;
  int quad = lane >> 4, m16 = lane & 15;
  __shared__ __align__(16) u16 lA[144*64];
  __shared__ __align__(16) u16 lB[256*64];
  size_t abase[3];
  #pragma unroll
  for (int r = 0; r < 3; r++){
    int chunk = tid + r*384; int j = chunk >> 3, cs = chunk & 7;
    int cc = cs ^ (j & 7);
    abase[r] = ((size_t)(n*2304 + qblk*144 + j))*320 + cc*8;
  }
  f32x4 acc[3][8];
  #pragma unroll
  for (int a = 0; a < 3; a++)
    #pragma unroll
    for (int c = 0; c < 8; c++) acc[a][c] = (f32x4){0.f,0.f,0.f,0.f};

  for (int kb = 0; kb < 5; kb++){
    __syncthreads();
    #pragma unroll
    for (int r = 0; r < 3; r++)
      gl16(&UT[abase[r] + kb*64], &lA[(tid + r*384)*8]);
    #pragma unroll
    for (int r = 0; r < 6; r++){
      int chunk = tid + r*384;
      if (chunk < 2048)
        gl16(&Wp[(size_t)(chunk >> 3)*320 + kb*64 + (chunk & 7)*8], &lB[chunk*8]);
    }
    __syncthreads();
    #pragma unroll
    for (int ks = 0; ks < 2; ks++){
      int sw = ((ks*4 + quad) ^ (lane & 7))*8;
      bf16x8 af[3], bfr[8];
      #pragma unroll
      for (int mt = 0; mt < 3; mt++)
        af[mt] = *(const bf16x8*)&lA[(wm*48 + mt*16 + m16)*64 + sw];
      #pragma unroll
      for (int nt = 0; nt < 8; nt++)
        bfr[nt] = *(const bf16x8*)&lB[(wn*128 + nt*16 + m16)*64 + sw];
      #pragma unroll
      for (int mt = 0; mt < 3; mt++)
        #pragma unroll
        for (int nt = 0; nt < 8; nt++)
          acc[mt][nt] = MFMA(af[mt], bfr[nt], acc[mt][nt]);
    }
  }
  #pragma unroll
  for (int mt = 0; mt < 3; mt++)
    #pragma unroll
    for (int nt = 0; nt < 8; nt++)
      #pragma unroll
      for (int r = 0; r < 4; r++){
        int q = qblk*144 + wm*48 + mt*16 + quad*4 + r;
        int oc = wn*128 + nt*16 + m16;
        int y = q / 48, x = q - y*48;
        int g = oc >> 5, ci = oc & 31;
        xh[(((size_t)((n*8+g)*56 + y+4))*56 + (x+4))*64 + ci] = f2b(acc[mt][nt][r]);
      }
}

// ---------------- fused 7-conv implicit GEMM (R3 structure) ----------------
// grid 256 = n(4) x g(8) x qb(8); 768 thr = 12 waves (wm 2 x 112oc, wn 6 x 48sp)
// tile 224 oc x 288 sp (6 rows). LDS 128KB: A dbuf 2x28KB + B dbuf 2x36KB.
__global__ __launch_bounds__(768) void k_conv(const u16* WB, const u16* xh,
                                              u16* Qb, u16* Kt, u16* Vb, u16* Gp){
  extern __shared__ __align__(16) u16 sm[];
  int b = blockIdx.x; int qb = b & 7; int gg = (b >> 3) & 7; int n = b >> 6;
  int tid = threadIdx.x; int lane = tid & 63; int wid = tid >> 6;
  int wm = wid & 1, wn = wid >> 1;
  int quad = lane >> 4, m16 = lane & 15;
  int y0 = qb*6;
  const u16* WBg = WB + (size_t)gg*81*14336;
  const u16* xg  = xh + (size_t)((n*8+gg)*3136)*64;
  int bsrc[3], bdst[3];
  #pragma unroll
  for (int r = 0; r < 3; r++){
    int c = tid + r*768;
    int dy = c / 384, rem = c % 384;
    int col = rem >> 3, cs = rem & 7;
    bsrc[r] = ((y0+dy)*56 + col)*64 + (cs ^ (col & 7))*8;
    bdst[r] = c*8;
  }
  f32x4 acc[7][3];
  #pragma unroll
  for (int a = 0; a < 7; a++)
    #pragma unroll
    for (int c = 0; c < 3; c++) acc[a][c] = (f32x4){0.f,0.f,0.f,0.f};

  {
    u16* A0 = sm;
    u16* B0 = sm + 28672;
    gl16(&WBg[tid*8],       &A0[tid*8]);
    gl16(&WBg[(tid+768)*8], &A0[(tid+768)*8]);
    if (tid < 256) gl16(&WBg[(tid+1536)*8], &A0[(tid+1536)*8]);
    #pragma unroll
    for (int r = 0; r < 3; r++)
      gl16(&xg[bsrc[r]], &B0[bdst[r]]);
  }

  int ky = 0, kx = 0;
  for (int kk = 0; kk < 81; kk++){
    __syncthreads();
    if (kk < 80){
      int kx1 = kx + 1, ky1 = ky;
      if (kx1 == 9){ kx1 = 0; ky1++; }
      int nb = (kk+1) & 1;
      u16* An = sm + nb*14336;
      u16* Bn = sm + 28672 + nb*18432;
      const u16* As = WBg + (size_t)(kk+1)*14336;
      gl16(&As[tid*8],       &An[tid*8]);
      gl16(&As[(tid+768)*8], &An[(tid+768)*8]);
      if (tid < 256){ gl16(&As[(tid+1536)*8], &An[(tid+1536)*8]); }
      int koff = (ky1*56 + kx1)*64;
      #pragma unroll
      for (int r = 0; r < 3; r++)
        gl16(&xg[bsrc[r] + koff], &Bn[bdst[r]]);
    }
    const u16* A = sm + (kk&1)*14336;
    const u16* B = sm + 28672 + (kk&1)*18432;
    #pragma unroll
    for (int ks = 0; ks < 2; ks++){
      bf16x8 af[7], bfr[3];
      #pragma unroll
      for (int mt = 0; mt < 7; mt++){
        int rr = wm*112 + mt*16 + m16;
        af[mt] = *(const bf16x8*)&A[rr*64 + (((ks*4+quad) ^ (rr&7))*8)];
      }
      #pragma unroll
      for (int nt = 0; nt < 3; nt++){
        int sp = wn*48 + nt*16 + m16;
        bfr[nt] = *(const bf16x8*)&B[sp*64 + (((ks*4+quad) ^ (sp&7))*8)];
      }
      #pragma unroll
      for (int mt = 0; mt < 7; mt++)
        #pragma unroll
        for (int nt = 0; nt < 3; nt++)
          acc[mt][nt] = MFMA(af[mt], bfr[nt], acc[mt][nt]);
    }
    kx++; if (kx == 9){ kx = 0; ky++; }
  }
  int y = y0 + wn;
  size_t ng = (size_t)(n*8 + gg);
  #pragma unroll
  for (int mt = 0; mt < 7; mt++){
    int ocb = wm*112 + mt*16 + quad*4;
    #pragma unroll
    for (int nt = 0; nt < 3; nt++){
      int x = nt*16 + m16;
      int q = y*48 + x;
      #pragma unroll
      for (int r = 0; r < 4; r++){
        float v = acc[mt][nt][r];
        int oc = ocb + r;
        int t7 = oc >> 5, ocl = oc & 31;
        if (t7 == 0){
          Qb[(ng*32 + ocl)*2304 + q] = f2b(v);
        } else if (t7 <= 2){
          if ((unsigned)(y-4) < 40u && (unsigned)(x-4) < 40u){
            int d = (y-4)*40 + (x-4);
            if (t7 == 1) Kt[(ng*1600 + d)*32 + ocl] = f2b(v);   // transposed [d][c]
            else         Vb[(ng*32 + ocl)*1600 + d] = f2b(v);
          }
        } else {
          Gp[((ng*4 + (t7-3))*32 + ocl)*2304 + q] = f2b(v);
        }
      }
    }
  }
}

// ---------------- attention + fused gate GEMM ----------------
// grid 576 = n(4) x g(8) x qb(18); 256 thr = 4 waves.
// Online softmax over 25 d-tiles of 64; then Ga[gate][32oc][128q] = Wa · O_norm via MFMA.
// LDS union (u16 idx): sQ[0,5120) (reused as sW), sK[5120,9216)x2, sV[9216,13312)x2,
//                      sP[13312,22528) per-wave stride 2304 (reused as sO[128][36]).
__global__ __launch_bounds__(256) void k_attn(const u16* Qb, const u16* Kt, const u16* Vb,
                                              u16* Ga, const void* tau,
                                              const void* Wai, const void* Waf,
                                              const void* Wag, const void* Wao,
                                              const int* flag){
  __shared__ __align__(16) u16 S[22528];
  __shared__ float sAl[128];
  __shared__ float sL[128];
  int b = blockIdx.x; int qb = b % 18; int g = (b / 18) & 7; int n = b / 144;
  int tid = threadIdx.x; int lane = tid & 63; int wid = tid >> 6;
  int quad = lane >> 4, m16 = lane & 15;
  int isbf = *flag;
  size_t ng = (size_t)(n*8 + g);
  const u16* Qg  = Qb + ng*32*2304;
  const u16* Ktg = Kt + ng*1600*32;
  const u16* Vg  = Vb + ng*32*1600;
  float tauv = ldin(tau, g, isbf);
  // stage Q tile [q][c] stride 40
  for (int i = 0; i < 16; i++){
    int el = tid + i*256; int c = el >> 7, q = el & 127;
    S[(q)*40 + c] = Qg[(size_t)c*2304 + qb*128 + q];
  }
  int kd = tid >> 2, kc = ((tid & 3) ^ (kd & 3))*8;
  int vc = tid >> 3, vd = ((tid & 7) ^ (vc & 7))*8;
  gl16(&Ktg[(size_t)kd*32 + kc], &S[5120 + tid*8]);
  gl16(&Vg[(size_t)vc*1600 + vd], &S[9216 + tid*8]);
  __syncthreads();
  bf16x8 aq[2];
  #pragma unroll
  for (int mt = 0; mt < 2; mt++)
    aq[mt] = *(const bf16x8*)&S[(wid*32 + mt*16 + m16)*40 + quad*8];
  __syncthreads();                      // all aq loaded -> sQ region reusable
  // stage Wa (4 gates x 32oc x 32ci) bf16 into sW = S[0,5120), row stride 40
  {
    const void* Ws[4] = {Wai, Waf, Wag, Wao};
    for (int i = tid; i < 4096; i += 256){
      int gate = i >> 10, oc = (i >> 5) & 31, ci = i & 31;
      S[gate*1280 + oc*40 + ci] = f2b(ldin(Ws[gate], (long long)(g*32 + oc)*32 + ci, isbf));
    }
  }

  float mrun[2][4], lrun[2][4];
  f32x4 oacc[2][2];
  #pragma unroll
  for (int a = 0; a < 2; a++)
    #pragma unroll
    for (int r = 0; r < 4; r++){ mrun[a][r] = -3e38f; lrun[a][r] = 0.f; }
  #pragma unroll
  for (int a = 0; a < 2; a++)
    #pragma unroll
    for (int c = 0; c < 2; c++) oacc[a][c] = (f32x4){0.f,0.f,0.f,0.f};
  u16* myP = &S[13312 + wid*2304];

  for (int dt = 0; dt < 25; dt++){
    __syncthreads();
    const u16* K = &S[5120 + (dt&1)*2048];
    const u16* V = &S[9216 + (dt&1)*2048];
    if (dt < 24){
      gl16(&Ktg[(size_t)((dt+1)*64 + kd)*32 + kc], &S[5120 + (1-(dt&1))*2048 + tid*8]);
      gl16(&Vg[(size_t)vc*1600 + (dt+1)*64 + vd], &S[9216 + (1-(dt&1))*2048 + tid*8]);
    }
    f32x4 sacc[2][4];
    #pragma unroll
    for (int a = 0; a < 2; a++)
      #pragma unroll
      for (int c = 0; c < 4; c++) sacc[a][c] = (f32x4){0.f,0.f,0.f,0.f};
    #pragma unroll
    for (int nt = 0; nt < 4; nt++){
      int d = nt*16 + m16;
      bf16x8 bk = *(const bf16x8*)&K[d*32 + ((quad ^ (d&3))*8)];
      #pragma unroll
      for (int mt = 0; mt < 2; mt++)
        sacc[mt][nt] = MFMA(aq[mt], bk, sacc[mt][nt]);
    }
    float alpha[2][4];
    #pragma unroll
    for (int mt = 0; mt < 2; mt++)
      #pragma unroll
      for (int r = 0; r < 4; r++){
        float v = fmaxf(fmaxf(sacc[mt][0][r], sacc[mt][1][r]),
                        fmaxf(sacc[mt][2][r], sacc[mt][3][r])) * tauv;
        v = fmaxf(v, __shfl_xor(v, 1));
        v = fmaxf(v, __shfl_xor(v, 2));
        v = fmaxf(v, __shfl_xor(v, 4));
        v = fmaxf(v, __shfl_xor(v, 8));
        float mnew = fmaxf(mrun[mt][r], v);
        alpha[mt][r] = __expf(mrun[mt][r] - mnew);
        mrun[mt][r] = mnew;
      }
    float ps[2][4] = {{0.f,0.f,0.f,0.f},{0.f,0.f,0.f,0.f}};
    #pragma unroll
    for (int mt = 0; mt < 2; mt++)
      #pragma unroll
      for (int nt = 0; nt < 4; nt++)
        #pragma unroll
        for (int r = 0; r < 4; r++){
          float p = __expf(sacc[mt][nt][r]*tauv - mrun[mt][r]);
          ps[mt][r] += p;
          myP[(mt*16 + quad*4 + r)*72 + nt*16 + m16] = f2b(p);
        }
    #pragma unroll
    for (int mt = 0; mt < 2; mt++)
      #pragma unroll
      for (int r = 0; r < 4; r++){
        float v = ps[mt][r];
        v += __shfl_xor(v, 1);
        v += __shfl_xor(v, 2);
        v += __shfl_xor(v, 4);
        v += __shfl_xor(v, 8);
        lrun[mt][r] = lrun[mt][r]*alpha[mt][r] + v;
      }
    if (m16 == 0){
      #pragma unroll
      for (int mt = 0; mt < 2; mt++)
        #pragma unroll
        for (int r = 0; r < 4; r++)
          sAl[wid*32 + mt*16 + quad*4 + r] = alpha[mt][r];
    }
    __syncthreads();
    float a0 = sAl[wid*32 + m16];
    float a1 = sAl[wid*32 + 16 + m16];
    #pragma unroll
    for (int mtc = 0; mtc < 2; mtc++){
      oacc[mtc][0] *= a0;
      oacc[mtc][1] *= a1;
    }
    #pragma unroll
    for (int ks = 0; ks < 2; ks++){
      bf16x8 av[2], bp[2];
      #pragma unroll
      for (int mtc = 0; mtc < 2; mtc++){
        int c = mtc*16 + m16;
        av[mtc] = *(const bf16x8*)&V[c*64 + (((ks*4+quad) ^ (c&7))*8)];
      }
      #pragma unroll
      for (int ntq = 0; ntq < 2; ntq++)
        bp[ntq] = *(const bf16x8*)&myP[(ntq*16 + m16)*72 + ks*32 + quad*8];
      #pragma unroll
      for (int mtc = 0; mtc < 2; mtc++)
        #pragma unroll
        for (int ntq = 0; ntq < 2; ntq++)
          oacc[mtc][ntq] = MFMA(av[mtc], bp[ntq], oacc[mtc][ntq]);
    }
  }
  if (m16 == 0){
    #pragma unroll
    for (int mt = 0; mt < 2; mt++)
      #pragma unroll
      for (int r = 0; r < 4; r++)
        sL[wid*32 + mt*16 + quad*4 + r] = lrun[mt][r];
  }
  __syncthreads();
  // write normalized O (bf16) to sO = S[13312 + q*36 + c]  (layout [q][c])
  {
    float linv0 = 1.0f / sL[wid*32 + m16];
    float linv1 = 1.0f / sL[wid*32 + 16 + m16];
    #pragma unroll
    for (int mtc = 0; mtc < 2; mtc++)
      #pragma unroll
      for (int ntq = 0; ntq < 2; ntq++){
        float linv = ntq ? linv1 : linv0;
        int q = wid*32 + ntq*16 + m16;
        #pragma unroll
        for (int r = 0; r < 4; r++){
          int c = mtc*16 + quad*4 + r;
          S[13312 + q*36 + c] = f2b(oacc[mtc][ntq][r] * linv);
        }
      }
  }
  __syncthreads();
  // gate GEMM: wave = gate; D[32oc][128q] = Wa(32x32) · O(32x128)
  {
    f32x4 gacc[2][8];
    #pragma unroll
    for (int mt = 0; mt < 2; mt++)
      #pragma unroll
      for (int nt = 0; nt < 8; nt++) gacc[mt][nt] = (f32x4){0.f,0.f,0.f,0.f};
    bf16x8 af[2];
    #pragma unroll
    for (int mt = 0; mt < 2; mt++)
      af[mt] = *(const bf16x8*)&S[wid*1280 + (mt*16 + m16)*40 + quad*8];
    #pragma unroll
    for (int nt = 0; nt < 8; nt++){
      bf16x8 bo = *(const bf16x8*)&S[13312 + (nt*16 + m16)*36 + quad*8];
      #pragma unroll
      for (int mt = 0; mt < 2; mt++)
        gacc[mt][nt] = MFMA(af[mt], bo, gacc[mt][nt]);
    }
    size_t gbase = ((ng*4 + wid)*32);
    #pragma unroll
    for (int mt = 0; mt < 2; mt++)
      #pragma unroll
      for (int nt = 0; nt < 8; nt++){
        int q = qb*128 + nt*16 + m16;
        #pragma unroll
        for (int r = 0; r < 4; r++){
          int oc = mt*16 + quad*4 + r;
          Ga[(gbase + oc)*2304 + q] = f2b(gacc[mt][nt][r]);
        }
      }
  }
}

// ---------------- pointwise LSTM finale ----------------
// grid 1152 x 256 thr, 8 elems/thread over [n][c=256][q=2304]
__global__ __launch_bounds__(256) void k_final(const u16* Ga, const u16* Gp,
    const void* bi, const void* bff, const void* bg, const void* bo,
    const void* cprev, void* out, const int* flag){
  int el = (blockIdx.x*256 + threadIdx.x)*8;
  int isbf = *flag;
  int q = el % 2304; int rest = el / 2304;
  int c = rest & 255; int n = rest >> 8;
  int g = c >> 5, oc = c & 31;
  size_t ng = (size_t)(n*8 + g);
  size_t base = ((ng*4)*32 + oc)*2304 + q;     // gate stride 73728
  float b0 = ldin(bi, c, isbf), b1 = ldin(bff, c, isbf);
  float b2 = ldin(bg, c, isbf), b3 = ldin(bo, c, isbf);
  bf16x8 ga0 = *(const bf16x8*)&Ga[base];
  bf16x8 ga1 = *(const bf16x8*)&Ga[base + 73728];
  bf16x8 ga2 = *(const bf16x8*)&Ga[base + 2*73728];
  bf16x8 ga3 = *(const bf16x8*)&Ga[base + 3*73728];
  bf16x8 gp0 = *(const bf16x8*)&Gp[base];
  bf16x8 gp1 = *(const bf16x8*)&Gp[base + 73728];
  bf16x8 gp2 = *(const bf16x8*)&Gp[base + 2*73728];
  bf16x8 gp3 = *(const bf16x8*)&Gp[base + 3*73728];
  float cp[8];
  if (isbf){
    bf16x8 cv = *(const bf16x8*)&((const u16*)cprev)[el];
    #pragma unroll
    for (int j = 0; j < 8; j++) cp[j] = b2f((u16)cv[j]);
  } else {
    f32x4v c0 = *(const f32x4v*)&((const float*)cprev)[el];
    f32x4v c1 = *(const f32x4v*)&((const float*)cprev)[el+4];
    #pragma unroll
    for (int j = 0; j < 4; j++){ cp[j] = c0[j]; cp[4+j] = c1[j]; }
  }
  float hv[8];
  #pragma unroll
  for (int j = 0; j < 8; j++){
    float a0 = b0 + b2f((u16)ga0[j]) + b2f((u16)gp0[j]);
    float a1 = b1 + b2f((u16)ga1[j]) + b2f((u16)gp1[j]);
    float a2 = b2 + b2f((u16)ga2[j]) + b2f((u16)gp2[j]);
    float a3 = b3 + b2f((u16)ga3[j]) + b2f((u16)gp3[j]);
    float gi = sigm(a0), gf = sigm(a1), gv = tanh_f(a2), go = sigm(a3);
    float cn = gf*cp[j] + gi*gv;
    hv[j] = go * tanh_f(cn);
  }
  if (isbf){
    bf16x8 o;
    #pragma unroll
    for (int j = 0; j < 8; j++) o[j] = (short)f2b(hv[j]);
    *(bf16x8*)&((u16*)out)[el] = o;
  } else {
    f32x4v o0, o1;
    #pragma unroll
    for (int j = 0; j < 4; j++){ o0[j] = hv[j]; o1[j] = hv[4+j]; }
    *(f32x4v*)&((float*)out)[el] = o0;
    *(f32x4v*)&((float*)out)[el+4] = o1;
  }
}

extern "C" void kernel_launch(void* const* d_in, const int* in_sizes, int n_in,
                              void* d_out, int out_size, void* d_ws, size_t ws_size,
                              hipStream_t stream){
  const void* inp  = d_in[0];
  const void* h    = d_in[1];
  const void* cpv  = d_in[2];
  const void* Wx   = d_in[3];
  const void* Wxg  = d_in[4];
  const void* tau  = d_in[5];
  const void* Wq   = d_in[6];
  const void* Wk   = d_in[7];
  const void* Wv   = d_in[8];
  const void* Wai  = d_in[9];  const void* Wxi = d_in[10]; const void* bi = d_in[11];
  const void* Waf  = d_in[12]; const void* Wxf = d_in[13]; const void* bff = d_in[14];
  const void* Wag  = d_in[15]; const void* Wxg2 = d_in[16]; const void* bg = d_in[17];
  const void* Wao  = d_in[18]; const void* Wxo = d_in[19]; const void* bo = d_in[20];

  char* ws = (char*)d_ws;
  int*  flag = (int*)(ws + OFF_FLAG);
  u16*  WB = (u16*)(ws + OFF_WB);
  u16*  Wp = (u16*)(ws + OFF_WP);
  u16*  UT = (u16*)(ws + OFF_UT);
  u16*  XH = (u16*)(ws + OFF_XH);
  u16*  Qb = (u16*)(ws + OFF_QB);
  u16*  Kt = (u16*)(ws + OFF_KT);
  u16*  Vb = (u16*)(ws + OFF_VB);
  u16*  Gp = (u16*)(ws + OFF_GP);
  u16*  Ga = (u16*)(ws + OFF_GA);

  (void)hipFuncSetAttribute(reinterpret_cast<const void*>(k_conv),
                            hipFuncAttributeMaxDynamicSharedMemorySize, 131072);

  (void)hipMemsetAsync(XH, 0, SZ_XH, stream);
  k_probe<<<1, 256, 0, stream>>>((const unsigned*)inp, flag);
  k_packw<<<1792, 256, 0, stream>>>(Wq, Wk, Wv, Wxi, Wxf, Wxg2, Wxo, WB, flag);
  k_packp<<<320, 256, 0, stream>>>(Wx, Wxg, Wp, flag);
  k_ut<<<360, 256, 0, stream>>>(inp, h, UT, XH, flag);
  k_proj<<<64, 384, 0, stream>>>(Wp, UT, XH);
  k_conv<<<256, 768, 131072, stream>>>(WB, XH, Qb, Kt, Vb, Gp);
  k_attn<<<576, 256, 0, stream>>>(Qb, Kt, Vb, Ga, tau, Wai, Waf, Wag, Wao, flag);
  k_final<<<1152, 256, 0, stream>>>(Ga, Gp, bi, bff, bg, bo, cpv, d_out, flag);
}

// Round 6
// 370.772 us; speedup vs baseline: 1.3607x; 1.2445x over previous
//
#include <hip/hip_runtime.h>
#include <stdint.h>

typedef unsigned short u16;
typedef float f32x4 __attribute__((ext_vector_type(4)));
typedef float f32x4v __attribute__((ext_vector_type(4)));
typedef short bf16x8 __attribute__((ext_vector_type(8)));

#define MFMA(a,b,c) __builtin_amdgcn_mfma_f32_16x16x32_bf16((a),(b),(c),0,0,0)

__device__ __forceinline__ u16 f2b(float f){
  union { float f; unsigned u; } x; x.f = f;
  unsigned r = x.u + 0x7FFFu + ((x.u >> 16) & 1u);   // RNE
  return (u16)(r >> 16);
}
__device__ __forceinline__ float b2f(u16 b){
  union { unsigned u; float f; } x; x.u = ((unsigned)b) << 16;
  return x.f;
}
__device__ __forceinline__ float ldin(const void* p, long long i, int isbf){
  return isbf ? b2f(((const u16*)p)[i]) : ((const float*)p)[i];
}
typedef const __attribute__((address_space(1))) void gas_t;
typedef __attribute__((address_space(3))) void sas_t;
__device__ __forceinline__ void gl16(const void* g, void* l){
  __builtin_amdgcn_global_load_lds((gas_t*)g, (sas_t*)l, 16, 0, 0);
}
__device__ __forceinline__ float sigm(float x){ return 1.f/(1.f + __expf(-x)); }
__device__ __forceinline__ float tanh_f(float x){
  float e2 = __expf(-2.f*fabsf(x));
  float t = (1.f - e2)/(1.f + e2);
  return copysignf(t, x);
}

// N=4 I=64 C=256 G=8 Cg=32 K=9 H=W=48 HW=2304 Hd=Wd=40 D=1600 pad=4 (56x56 padded)
static constexpr size_t OFF_FLAG = 0;
static constexpr size_t OFF_WB = 256;                     // conv w bf16 [g][81][224][64]
static constexpr size_t SZ_WB  = (size_t)8*81*224*64*2;
static constexpr size_t OFF_WP = OFF_WB + SZ_WB;          // proj w bf16 [256][320]
static constexpr size_t SZ_WP  = (size_t)256*320*2;
static constexpr size_t OFF_UT = OFF_WP + SZ_WP;          // [n][2304][320] bf16
static constexpr size_t SZ_UT  = (size_t)4*2304*320*2;
static constexpr size_t OFF_XH = OFF_UT + SZ_UT;          // [n][g][56][56][64] bf16
static constexpr size_t SZ_XH  = (size_t)32*3136*64*2;
static constexpr size_t OFF_QB = OFF_XH + SZ_XH;          // [n][g][32][2304] bf16
static constexpr size_t SZ_QB  = (size_t)32*32*2304*2;
static constexpr size_t OFF_KT = OFF_QB + SZ_QB;          // [n][g][1600][32] bf16 (K transposed)
static constexpr size_t SZ_KT  = (size_t)32*1600*32*2;
static constexpr size_t OFF_VB = OFF_KT + SZ_KT;          // [n][g][32][1600] bf16
static constexpr size_t OFF_GP = OFF_VB + SZ_KT;          // [n][g][4][32][2304] bf16 conv gate pre-acts
static constexpr size_t SZ_GP  = (size_t)32*4*32*2304*2;
static constexpr size_t OFF_GA = OFF_GP + SZ_GP;          // [n][g][4][32][2304] bf16 attn gate pre-acts
static constexpr size_t SZ_GA  = SZ_GP;

// ---------------- probe: detect bf16 vs fp32 inputs ----------------
__global__ void k_probe(const unsigned* u, int* flag){
  int t = threadIdx.x;
  unsigned v = u[t];
  unsigned e = (v >> 7) & 0xFF;
  int is = (e >= 0x70 && e <= 0x88) ? 1 : 0;
  unsigned long long m = __ballot(is);
  __shared__ int cnt[4];
  if ((t & 63) == 0) cnt[t >> 6] = __popcll(m);
  __syncthreads();
  if (t == 0) *flag = (cnt[0]+cnt[1]+cnt[2]+cnt[3] >= 128) ? 1 : 0;
}

// ---------------- pack conv weights ----------------
__global__ void k_packw(const void* Wq, const void* Wk, const void* Wv,
                        const void* Wi, const void* Wf, const void* Wg,
                        const void* Wo, u16* WB, const int* flag){
  int b = blockIdx.x; int ocl = b & 31; int tt = (b >> 5) % 7; int g = b / 224;
  int tid = threadIdx.x; int isbf = *flag;
  const void* srcs[7] = {Wq, Wk, Wv, Wi, Wf, Wg, Wo};
  const void* src = srcs[tt];
  __shared__ float s[5184];
  long long base = (long long)(g*32 + ocl) * 5184;
  for (int i = tid; i < 5184; i += 256) s[i] = ldin(src, base + i, isbf);
  __syncthreads();
  int oc = tt*32 + ocl;
  for (int i = tid; i < 5184; i += 256){
    int kk = i >> 6, ci = i & 63;
    int pos = ((((ci >> 3) ^ (ocl & 7)) << 3) | (ci & 7));
    WB[((size_t)(g*81 + kk)*224 + oc)*64 + pos] = f2b(s[ci*81 + kk]);
  }
}

// ---------------- pack proj weights ----------------
__global__ void k_packp(const void* Wx, const void* Wxg, u16* Wp, const int* flag){
  int el = blockIdx.x*256 + threadIdx.x;
  int isbf = *flag;
  if (el >= 81920) return;
  int oc = el / 320, k = el % 320;
  float v = (k < 64) ? ldin(Wx, (long long)oc*64 + k, isbf)
                     : ldin(Wxg, (long long)oc*256 + (k - 64), isbf);
  int win = k >> 6, pos = k & 63;
  int dpos = (win << 6) | ((((pos >> 3) ^ (oc & 7)) << 3)) | (pos & 7);
  Wp[(size_t)oc*320 + dpos] = f2b(v);
}

// ---------------- build U_T + h-part of xh_pad ----------------
__global__ void k_ut(const void* inp, const void* h, u16* UT, u16* xh, const int* flag){
  int b = blockIdx.x; int qb = b % 18; int s = (b / 18) % 5; int n = b / 90;
  int tid = threadIdx.x; int isbf = *flag;
  __shared__ float sb[64][129];
  const void* src = (s == 0) ? inp : h;
  long long base = (s == 0) ? (long long)n*64*2304 : ((long long)n*256 + (s-1)*64)*2304;
  for (int i = 0; i < 32; i++){
    int el = tid + i*256; int r = el >> 7, q = el & 127;
    sb[r][q] = ldin(src, base + (long long)r*2304 + qb*128 + q, isbf);
  }
  __syncthreads();
  int koff = (s == 0) ? 0 : 64 + (s-1)*64;
  for (int i = 0; i < 4; i++){
    int chunk = tid + i*256;
    int q = chunk >> 3, c8 = chunk & 7;
    bf16x8 v;
    #pragma unroll
    for (int j = 0; j < 8; j++) v[j] = (short)f2b(sb[c8*8 + j][q]);
    *(bf16x8*)&UT[((size_t)(n*2304 + qb*128 + q))*320 + koff + c8*8] = v;
  }
  if (s > 0){
    for (int i = 0; i < 4; i++){
      int chunk = tid + i*256;
      int q = chunk >> 3, gg = (chunk >> 2) & 1, seg = chunk & 3;
      int g = (s-1)*2 + gg;
      int qg = qb*128 + q; int y = qg / 48, x = qg - y*48;
      bf16x8 v;
      #pragma unroll
      for (int j = 0; j < 8; j++) v[j] = (short)f2b(sb[gg*32 + seg*8 + j][q]);
      *(bf16x8*)&xh[(((size_t)((n*8+g)*56 + y+4))*56 + (x+4))*64 + 32 + seg*8] = v;
    }
  }
}

// ---------------- proj GEMM ----------------
__global__ __launch_bounds__(384) void k_proj(const u16* Wp, const u16* UT, u16* xh){
  int b = blockIdx.x; int qblk = b & 15; int n = b >> 4;
  int tid = threadIdx.x; int lane = tid & 63; int wid = tid >> 6;
  int wm = wid % 3, wn = wid / 3;
  int quad = lane >> 4, m16 = lane & 15;
  __shared__ __align__(16) u16 lA[144*64];
  __shared__ __align__(16) u16 lB[256*64];
  size_t abase[3];
  #pragma unroll
  for (int r = 0; r < 3; r++){
    int chunk = tid + r*384; int j = chunk >> 3, cs = chunk & 7;
    int cc = cs ^ (j & 7);
    abase[r] = ((size_t)(n*2304 + qblk*144 + j))*320 + cc*8;
  }
  f32x4 acc[3][8];
  #pragma unroll
  for (int a = 0; a < 3; a++)
    #pragma unroll
    for (int c = 0; c < 8; c++) acc[a][c] = (f32x4){0.f,0.f,0.f,0.f};

  for (int kb = 0; kb < 5; kb++){
    __syncthreads();
    #pragma unroll
    for (int r = 0; r < 3; r++)
      gl16(&UT[abase[r] + kb*64], &lA[(tid + r*384)*8]);
    #pragma unroll
    for (int r = 0; r < 6; r++){
      int chunk = tid + r*384;
      if (chunk < 2048)
        gl16(&Wp[(size_t)(chunk >> 3)*320 + kb*64 + (chunk & 7)*8], &lB[chunk*8]);
    }
    __syncthreads();
    #pragma unroll
    for (int ks = 0; ks < 2; ks++){
      int sw = ((ks*4 + quad) ^ (lane & 7))*8;
      bf16x8 af[3], bfr[8];
      #pragma unroll
      for (int mt = 0; mt < 3; mt++)
        af[mt] = *(const bf16x8*)&lA[(wm*48 + mt*16 + m16)*64 + sw];
      #pragma unroll
      for (int nt = 0; nt < 8; nt++)
        bfr[nt] = *(const bf16x8*)&lB[(wn*128 + nt*16 + m16)*64 + sw];
      #pragma unroll
      for (int mt = 0; mt < 3; mt++)
        #pragma unroll
        for (int nt = 0; nt < 8; nt++)
          acc[mt][nt] = MFMA(af[mt], bfr[nt], acc[mt][nt]);
    }
  }
  #pragma unroll
  for (int mt = 0; mt < 3; mt++)
    #pragma unroll
    for (int nt = 0; nt < 8; nt++)
      #pragma unroll
      for (int r = 0; r < 4; r++){
        int q = qblk*144 + wm*48 + mt*16 + quad*4 + r;
        int oc = wn*128 + nt*16 + m16;
        int y = q / 48, x = q - y*48;
        int g = oc >> 5, ci = oc & 31;
        xh[(((size_t)((n*8+g)*56 + y+4))*56 + (x+4))*64 + ci] = f2b(acc[mt][nt][r]);
      }
}

// ---------------- fused 7-conv implicit GEMM (R3 structure) ----------------
__global__ __launch_bounds__(768) void k_conv(const u16* WB, const u16* xh,
                                              u16* Qb, u16* Kt, u16* Vb, u16* Gp){
  extern __shared__ __align__(16) u16 sm[];
  int b = blockIdx.x; int qb = b & 7; int gg = (b >> 3) & 7; int n = b >> 6;
  int tid = threadIdx.x; int lane = tid & 63; int wid = tid >> 6;
  int wm = wid & 1, wn = wid >> 1;
  int quad = lane >> 4, m16 = lane & 15;
  int y0 = qb*6;
  const u16* WBg = WB + (size_t)gg*81*14336;
  const u16* xg  = xh + (size_t)((n*8+gg)*3136)*64;
  int bsrc[3], bdst[3];
  #pragma unroll
  for (int r = 0; r < 3; r++){
    int c = tid + r*768;
    int dy = c / 384, rem = c % 384;
    int col = rem >> 3, cs = rem & 7;
    bsrc[r] = ((y0+dy)*56 + col)*64 + (cs ^ (col & 7))*8;
    bdst[r] = c*8;
  }
  f32x4 acc[7][3];
  #pragma unroll
  for (int a = 0; a < 7; a++)
    #pragma unroll
    for (int c = 0; c < 3; c++) acc[a][c] = (f32x4){0.f,0.f,0.f,0.f};

  {
    u16* A0 = sm;
    u16* B0 = sm + 28672;
    gl16(&WBg[tid*8],       &A0[tid*8]);
    gl16(&WBg[(tid+768)*8], &A0[(tid+768)*8]);
    if (tid < 256) gl16(&WBg[(tid+1536)*8], &A0[(tid+1536)*8]);
    #pragma unroll
    for (int r = 0; r < 3; r++)
      gl16(&xg[bsrc[r]], &B0[bdst[r]]);
  }

  int ky = 0, kx = 0;
  for (int kk = 0; kk < 81; kk++){
    __syncthreads();
    if (kk < 80){
      int kx1 = kx + 1, ky1 = ky;
      if (kx1 == 9){ kx1 = 0; ky1++; }
      int nb = (kk+1) & 1;
      u16* An = sm + nb*14336;
      u16* Bn = sm + 28672 + nb*18432;
      const u16* As = WBg + (size_t)(kk+1)*14336;
      gl16(&As[tid*8],       &An[tid*8]);
      gl16(&As[(tid+768)*8], &An[(tid+768)*8]);
      if (tid < 256){ gl16(&As[(tid+1536)*8], &An[(tid+1536)*8]); }
      int koff = (ky1*56 + kx1)*64;
      #pragma unroll
      for (int r = 0; r < 3; r++)
        gl16(&xg[bsrc[r] + koff], &Bn[bdst[r]]);
    }
    const u16* A = sm + (kk&1)*14336;
    const u16* B = sm + 28672 + (kk&1)*18432;
    #pragma unroll
    for (int ks = 0; ks < 2; ks++){
      bf16x8 af[7], bfr[3];
      #pragma unroll
      for (int mt = 0; mt < 7; mt++){
        int rr = wm*112 + mt*16 + m16;
        af[mt] = *(const bf16x8*)&A[rr*64 + (((ks*4+quad) ^ (rr&7))*8)];
      }
      #pragma unroll
      for (int nt = 0; nt < 3; nt++){
        int sp = wn*48 + nt*16 + m16;
        bfr[nt] = *(const bf16x8*)&B[sp*64 + (((ks*4+quad) ^ (sp&7))*8)];
      }
      #pragma unroll
      for (int mt = 0; mt < 7; mt++)
        #pragma unroll
        for (int nt = 0; nt < 3; nt++)
          acc[mt][nt] = MFMA(af[mt], bfr[nt], acc[mt][nt]);
    }
    kx++; if (kx == 9){ kx = 0; ky++; }
  }
  int y = y0 + wn;
  size_t ng = (size_t)(n*8 + gg);
  #pragma unroll
  for (int mt = 0; mt < 7; mt++){
    int ocb = wm*112 + mt*16 + quad*4;
    #pragma unroll
    for (int nt = 0; nt < 3; nt++){
      int x = nt*16 + m16;
      int q = y*48 + x;
      #pragma unroll
      for (int r = 0; r < 4; r++){
        float v = acc[mt][nt][r];
        int oc = ocb + r;
        int t7 = oc >> 5, ocl = oc & 31;
        if (t7 == 0){
          Qb[(ng*32 + ocl)*2304 + q] = f2b(v);
        } else if (t7 <= 2){
          if ((unsigned)(y-4) < 40u && (unsigned)(x-4) < 40u){
            int d = (y-4)*40 + (x-4);
            if (t7 == 1) Kt[(ng*1600 + d)*32 + ocl] = f2b(v);   // transposed [d][c]
            else         Vb[(ng*32 + ocl)*1600 + d] = f2b(v);
          }
        } else {
          Gp[((ng*4 + (t7-3))*32 + ocl)*2304 + q] = f2b(v);
        }
      }
    }
  }
}

// ---------------- attention (no-max softmax, S^T orientation) + fused gate GEMM ----------------
// grid 576 = n(4) x g(8) x qb(18); 256 thr = 4 waves, 32 q each; 25 d-tiles of 64.
// l computed via ones-row MFMA (oacc[2]); per-wave P round-trip, ONE barrier per tile.
// LDS (u16 idx): sQ/sW [0,5120); sK 2x2048 [5120,9216); sV 2x2048 [9216,13312);
//                sP per-wave [32][72] stride 2304 [13312,22528); sO reuse [128][48] at 13312.
__global__ __launch_bounds__(256, 3) void k_attn(const u16* Qb, const u16* Kt, const u16* Vb,
                                                 u16* Ga, const void* tau,
                                                 const void* Wai, const void* Waf,
                                                 const void* Wag, const void* Wao,
                                                 const int* flag){
  __shared__ __align__(16) u16 S[22528];
  int b = blockIdx.x; int qb = b % 18; int g = (b / 18) & 7; int n = b / 144;
  int tid = threadIdx.x; int lane = tid & 63; int wid = tid >> 6;
  int quad = lane >> 4, m16 = lane & 15;
  int isbf = *flag;
  size_t ng = (size_t)(n*8 + g);
  const u16* Qg  = Qb + ng*32*2304;
  const u16* Ktg = Kt + ng*1600*32;
  const u16* Vg  = Vb + ng*32*1600;
  float tauv = ldin(tau, g, isbf);
  // stage Q [q][c] stride 40
  for (int i = 0; i < 16; i++){
    int el = tid + i*256; int c = el >> 7, q = el & 127;
    S[q*40 + c] = Qg[(size_t)c*2304 + qb*128 + q];
  }
  // K: LDS [d64][c32], chunk p holds src chunk p^((d>>1)&3); V: [c32][d64], chunk p holds p^(c&7)
  int kd = tid >> 2, kc = ((tid & 3) ^ ((kd >> 1) & 3))*8;
  int vc = tid >> 3, vd = ((tid & 7) ^ (vc & 7))*8;
  gl16(&Ktg[(size_t)kd*32 + kc], &S[5120 + tid*8]);
  gl16(&Vg[(size_t)vc*1600 + vd], &S[9216 + tid*8]);
  __syncthreads();
  bf16x8 aq[2];
  #pragma unroll
  for (int mtq = 0; mtq < 2; mtq++)
    aq[mtq] = *(const bf16x8*)&S[(wid*32 + mtq*16 + m16)*40 + quad*8];
  __syncthreads();                      // aq in regs -> sQ region reusable
  // stage Wa (4 gates x 32oc x 32ci) into S[0,5120), row stride 40
  {
    const void* Ws[4] = {Wai, Waf, Wag, Wao};
    for (int i = tid; i < 4096; i += 256){
      int gate = i >> 10, oc = (i >> 5) & 31, ci = i & 31;
      S[gate*1280 + oc*40 + ci] = f2b(ldin(Ws[gate], (long long)(g*32 + oc)*32 + ci, isbf));
    }
  }
  f32x4 oacc[3][2];                     // [c16-group 0..1, ones][q16-group]
  #pragma unroll
  for (int a = 0; a < 3; a++)
    #pragma unroll
    for (int c = 0; c < 2; c++) oacc[a][c] = (f32x4){0.f,0.f,0.f,0.f};
  bf16x8 vones;
  #pragma unroll
  for (int j = 0; j < 8; j++) vones[j] = (short)0x3F80;
  u16* myP = &S[13312 + wid*2304];

  for (int dt = 0; dt < 25; dt++){
    __syncthreads();                     // buffers[dt&1] staged; prev reads retired
    const u16* K = &S[5120 + (dt&1)*2048];
    const u16* V = &S[9216 + (dt&1)*2048];
    if (dt < 24){
      gl16(&Ktg[(size_t)((dt+1)*64 + kd)*32 + kc], &S[5120 + (1-(dt&1))*2048 + tid*8]);
      gl16(&Vg[(size_t)vc*1600 + (dt+1)*64 + vd], &S[9216 + (1-(dt&1))*2048 + tid*8]);
    }
    // S^T = K·Q^T: rows d, cols q. lane reg r: d = nt*16+quad*4+r, q = mtq*16+m16
    f32x4 sacc[4][2];
    #pragma unroll
    for (int a = 0; a < 4; a++)
      #pragma unroll
      for (int c = 0; c < 2; c++) sacc[a][c] = (f32x4){0.f,0.f,0.f,0.f};
    #pragma unroll
    for (int nt = 0; nt < 4; nt++){
      int d = nt*16 + m16;
      bf16x8 ak = *(const bf16x8*)&K[d*32 + ((quad ^ ((m16 >> 1) & 3))*8)];
      #pragma unroll
      for (int mtq = 0; mtq < 2; mtq++)
        sacc[nt][mtq] = MFMA(ak, aq[mtq], sacc[nt][mtq]);
    }
    // P = exp(tau*S) (no max-sub; |tau*S| ~ 0.04 by construction), pack 4 -> b64
    #pragma unroll
    for (int nt = 0; nt < 4; nt++)
      #pragma unroll
      for (int mtq = 0; mtq < 2; mtq++){
        unsigned u0 = __float_as_uint(__expf(sacc[nt][mtq][0]*tauv));
        unsigned u1 = __float_as_uint(__expf(sacc[nt][mtq][1]*tauv));
        unsigned u2 = __float_as_uint(__expf(sacc[nt][mtq][2]*tauv));
        unsigned u3 = __float_as_uint(__expf(sacc[nt][mtq][3]*tauv));
        uint2 pk;
        pk.x = (u0 >> 16) | (u1 & 0xFFFF0000u);
        pk.y = (u2 >> 16) | (u3 & 0xFFFF0000u);
        *(uint2*)&myP[(mtq*16 + m16)*72 + nt*16 + quad*4] = pk;
      }
    // O^T += V·P^T (+ ones row -> l). Per-wave P: DS in-order, no barrier.
    #pragma unroll
    for (int ks = 0; ks < 2; ks++){
      bf16x8 av[2], bp[2];
      #pragma unroll
      for (int mtc = 0; mtc < 2; mtc++){
        int c = mtc*16 + m16;
        av[mtc] = *(const bf16x8*)&V[c*64 + (((ks*4+quad) ^ (c&7))*8)];
      }
      #pragma unroll
      for (int ntq = 0; ntq < 2; ntq++)
        bp[ntq] = *(const bf16x8*)&myP[(ntq*16 + m16)*72 + ks*32 + quad*8];
      #pragma unroll
      for (int mtc = 0; mtc < 2; mtc++)
        #pragma unroll
        for (int ntq = 0; ntq < 2; ntq++)
          oacc[mtc][ntq] = MFMA(av[mtc], bp[ntq], oacc[mtc][ntq]);
      #pragma unroll
      for (int ntq = 0; ntq < 2; ntq++)
        oacc[2][ntq] = MFMA(vones, bp[ntq], oacc[2][ntq]);
    }
  }
  // l_q replicated in every lane of oacc[2][ntq] (ones-A makes all rows equal)
  float linv[2];
  linv[0] = 1.0f / oacc[2][0][0];
  linv[1] = 1.0f / oacc[2][1][0];
  __syncthreads();                       // all waves done with P/K/V reads
  // write normalized O to sO[128][48] at S[13312): b64 of 4 consecutive c
  #pragma unroll
  for (int mtc = 0; mtc < 2; mtc++)
    #pragma unroll
    for (int ntq = 0; ntq < 2; ntq++){
      int q = wid*32 + ntq*16 + m16;
      unsigned u0 = __float_as_uint(oacc[mtc][ntq][0] * linv[ntq]);
      unsigned u1 = __float_as_uint(oacc[mtc][ntq][1] * linv[ntq]);
      unsigned u2 = __float_as_uint(oacc[mtc][ntq][2] * linv[ntq]);
      unsigned u3 = __float_as_uint(oacc[mtc][ntq][3] * linv[ntq]);
      uint2 pk;
      pk.x = (u0 >> 16) | (u1 & 0xFFFF0000u);
      pk.y = (u2 >> 16) | (u3 & 0xFFFF0000u);
      *(uint2*)&S[13312 + q*48 + mtc*16 + quad*4] = pk;
    }
  __syncthreads();
  // gate GEMM: wave = gate; D[32oc][128q] = Wa(32x32) · O(32x128)
  {
    f32x4 gacc[2][8];
    #pragma unroll
    for (int mt = 0; mt < 2; mt++)
      #pragma unroll
      for (int nt = 0; nt < 8; nt++) gacc[mt][nt] = (f32x4){0.f,0.f,0.f,0.f};
    bf16x8 af[2];
    #pragma unroll
    for (int mt = 0; mt < 2; mt++)
      af[mt] = *(const bf16x8*)&S[wid*1280 + (mt*16 + m16)*40 + quad*8];
    #pragma unroll
    for (int nt = 0; nt < 8; nt++){
      bf16x8 bo = *(const bf16x8*)&S[13312 + (nt*16 + m16)*48 + quad*8];
      #pragma unroll
      for (int mt = 0; mt < 2; mt++)
        gacc[mt][nt] = MFMA(af[mt], bo, gacc[mt][nt]);
    }
    size_t gbase = ((ng*4 + wid)*32);
    #pragma unroll
    for (int mt = 0; mt < 2; mt++)
      #pragma unroll
      for (int nt = 0; nt < 8; nt++){
        int q = qb*128 + nt*16 + m16;
        #pragma unroll
        for (int r = 0; r < 4; r++){
          int oc = mt*16 + quad*4 + r;
          Ga[(gbase + oc)*2304 + q] = f2b(gacc[mt][nt][r]);
        }
      }
  }
}

// ---------------- pointwise LSTM finale ----------------
__global__ __launch_bounds__(256) void k_final(const u16* Ga, const u16* Gp,
    const void* bi, const void* bff, const void* bg, const void* bo,
    const void* cprev, void* out, const int* flag){
  int el = (blockIdx.x*256 + threadIdx.x)*8;
  int isbf = *flag;
  int q = el % 2304; int rest = el / 2304;
  int c = rest & 255; int n = rest >> 8;
  int g = c >> 5, oc = c & 31;
  size_t ng = (size_t)(n*8 + g);
  size_t base = ((ng*4)*32 + oc)*2304 + q;     // gate stride 73728
  float b0 = ldin(bi, c, isbf), b1 = ldin(bff, c, isbf);
  float b2 = ldin(bg, c, isbf), b3 = ldin(bo, c, isbf);
  bf16x8 ga0 = *(const bf16x8*)&Ga[base];
  bf16x8 ga1 = *(const bf16x8*)&Ga[base + 73728];
  bf16x8 ga2 = *(const bf16x8*)&Ga[base + 2*73728];
  bf16x8 ga3 = *(const bf16x8*)&Ga[base + 3*73728];
  bf16x8 gp0 = *(const bf16x8*)&Gp[base];
  bf16x8 gp1 = *(const bf16x8*)&Gp[base + 73728];
  bf16x8 gp2 = *(const bf16x8*)&Gp[base + 2*73728];
  bf16x8 gp3 = *(const bf16x8*)&Gp[base + 3*73728];
  float cp[8];
  if (isbf){
    bf16x8 cv = *(const bf16x8*)&((const u16*)cprev)[el];
    #pragma unroll
    for (int j = 0; j < 8; j++) cp[j] = b2f((u16)cv[j]);
  } else {
    f32x4v c0 = *(const f32x4v*)&((const float*)cprev)[el];
    f32x4v c1 = *(const f32x4v*)&((const float*)cprev)[el+4];
    #pragma unroll
    for (int j = 0; j < 4; j++){ cp[j] = c0[j]; cp[4+j] = c1[j]; }
  }
  float hv[8];
  #pragma unroll
  for (int j = 0; j < 8; j++){
    float a0 = b0 + b2f((u16)ga0[j]) + b2f((u16)gp0[j]);
    float a1 = b1 + b2f((u16)ga1[j]) + b2f((u16)gp1[j]);
    float a2 = b2 + b2f((u16)ga2[j]) + b2f((u16)gp2[j]);
    float a3 = b3 + b2f((u16)ga3[j]) + b2f((u16)gp3[j]);
    float gi = sigm(a0), gf = sigm(a1), gv = tanh_f(a2), go = sigm(a3);
    float cn = gf*cp[j] + gi*gv;
    hv[j] = go * tanh_f(cn);
  }
  if (isbf){
    bf16x8 o;
    #pragma unroll
    for (int j = 0; j < 8; j++) o[j] = (short)f2b(hv[j]);
    *(bf16x8*)&((u16*)out)[el] = o;
  } else {
    f32x4v o0, o1;
    #pragma unroll
    for (int j = 0; j < 4; j++){ o0[j] = hv[j]; o1[j] = hv[4+j]; }
    *(f32x4v*)&((float*)out)[el] = o0;
    *(f32x4v*)&((float*)out)[el+4] = o1;
  }
}

extern "C" void kernel_launch(void* const* d_in, const int* in_sizes, int n_in,
                              void* d_out, int out_size, void* d_ws, size_t ws_size,
                              hipStream_t stream){
  const void* inp  = d_in[0];
  const void* h    = d_in[1];
  const void* cpv  = d_in[2];
  const void* Wx   = d_in[3];
  const void* Wxg  = d_in[4];
  const void* tau  = d_in[5];
  const void* Wq   = d_in[6];
  const void* Wk   = d_in[7];
  const void* Wv   = d_in[8];
  const void* Wai  = d_in[9];  const void* Wxi = d_in[10]; const void* bi = d_in[11];
  const void* Waf  = d_in[12]; const void* Wxf = d_in[13]; const void* bff = d_in[14];
  const void* Wag  = d_in[15]; const void* Wxg2 = d_in[16]; const void* bg = d_in[17];
  const void* Wao  = d_in[18]; const void* Wxo = d_in[19]; const void* bo = d_in[20];

  char* ws = (char*)d_ws;
  int*  flag = (int*)(ws + OFF_FLAG);
  u16*  WB = (u16*)(ws + OFF_WB);
  u16*  Wp = (u16*)(ws + OFF_WP);
  u16*  UT = (u16*)(ws + OFF_UT);
  u16*  XH = (u16*)(ws + OFF_XH);
  u16*  Qb = (u16*)(ws + OFF_QB);
  u16*  Kt = (u16*)(ws + OFF_KT);
  u16*  Vb = (u16*)(ws + OFF_VB);
  u16*  Gp = (u16*)(ws + OFF_GP);
  u16*  Ga = (u16*)(ws + OFF_GA);

  (void)hipFuncSetAttribute(reinterpret_cast<const void*>(k_conv),
                            hipFuncAttributeMaxDynamicSharedMemorySize, 131072);

  (void)hipMemsetAsync(XH, 0, SZ_XH, stream);
  k_probe<<<1, 256, 0, stream>>>((const unsigned*)inp, flag);
  k_packw<<<1792, 256, 0, stream>>>(Wq, Wk, Wv, Wxi, Wxf, Wxg2, Wxo, WB, flag);
  k_packp<<<320, 256, 0, stream>>>(Wx, Wxg, Wp, flag);
  k_ut<<<360, 256, 0, stream>>>(inp, h, UT, XH, flag);
  k_proj<<<64, 384, 0, stream>>>(Wp, UT, XH);
  k_conv<<<256, 768, 131072, stream>>>(WB, XH, Qb, Kt, Vb, Gp);
  k_attn<<<576, 256, 0, stream>>>(Qb, Kt, Vb, Ga, tau, Wai, Waf, Wag, Wao, flag);
  k_final<<<1152, 256, 0, stream>>>(Ga, Gp, bi, bff, bg, bo, cpv, d_out, flag);
}

// Round 7
// 360.838 us; speedup vs baseline: 1.3982x; 1.0275x over previous
//
#include <hip/hip_runtime.h>
#include <stdint.h>

typedef unsigned short u16;
typedef float f32x4 __attribute__((ext_vector_type(4)));
typedef float f32x4v __attribute__((ext_vector_type(4)));
typedef short bf16x8 __attribute__((ext_vector_type(8)));

#define MFMA(a,b,c) __builtin_amdgcn_mfma_f32_16x16x32_bf16((a),(b),(c),0,0,0)

__device__ __forceinline__ u16 f2b(float f){
  union { float f; unsigned u; } x; x.f = f;
  unsigned r = x.u + 0x7FFFu + ((x.u >> 16) & 1u);   // RNE
  return (u16)(r >> 16);
}
__device__ __forceinline__ float b2f(u16 b){
  union { unsigned u; float f; } x; x.u = ((unsigned)b) << 16;
  return x.f;
}
__device__ __forceinline__ float ldin(const void* p, long long i, int isbf){
  return isbf ? b2f(((const u16*)p)[i]) : ((const float*)p)[i];
}
typedef const __attribute__((address_space(1))) void gas_t;
typedef __attribute__((address_space(3))) void sas_t;
__device__ __forceinline__ void gl16(const void* g, void* l){
  __builtin_amdgcn_global_load_lds((gas_t*)g, (sas_t*)l, 16, 0, 0);
}
__device__ __forceinline__ float sigm(float x){ return 1.f/(1.f + __expf(-x)); }
__device__ __forceinline__ float tanh_f(float x){
  float e2 = __expf(-2.f*fabsf(x));
  float t = (1.f - e2)/(1.f + e2);
  return copysignf(t, x);
}

// N=4 I=64 C=256 G=8 Cg=32 K=9 H=W=48 HW=2304 Hd=Wd=40 D=1600 pad=4 (56x56 padded)
static constexpr size_t OFF_FLAG = 0;
static constexpr size_t OFF_WB = 256;                     // conv w bf16 [g][81][224][64]
static constexpr size_t SZ_WB  = (size_t)8*81*224*64*2;
static constexpr size_t OFF_WP = OFF_WB + SZ_WB;          // proj w bf16 [256][320]
static constexpr size_t SZ_WP  = (size_t)256*320*2;
static constexpr size_t OFF_UT = OFF_WP + SZ_WP;          // [n][2304][320] bf16
static constexpr size_t SZ_UT  = (size_t)4*2304*320*2;
static constexpr size_t OFF_XH = OFF_UT + SZ_UT;          // [n][g][56][56][64] bf16
static constexpr size_t SZ_XH  = (size_t)32*3136*64*2;
static constexpr size_t OFF_QB = OFF_XH + SZ_XH;          // [n][g][32][2304] bf16
static constexpr size_t SZ_QB  = (size_t)32*32*2304*2;
static constexpr size_t OFF_KT = OFF_QB + SZ_QB;          // [n][g][1600][32] bf16 (K transposed)
static constexpr size_t SZ_KT  = (size_t)32*1600*32*2;
static constexpr size_t OFF_VB = OFF_KT + SZ_KT;          // [n][g][32][1600] bf16
static constexpr size_t OFF_GP = OFF_VB + SZ_KT;          // [n][g][4][32][2304] bf16 conv gate pre-acts
static constexpr size_t SZ_GP  = (size_t)32*4*32*2304*2;
static constexpr size_t OFF_GA = OFF_GP + SZ_GP;          // [n][g][4][32][2304] bf16 attn gate pre-acts
static constexpr size_t SZ_GA  = SZ_GP;

// ---------------- fused prep: packw [0,1792) | packp [1792,2112) | ut [2112,2472) ----------------
// dtype probe computed inline per block (no cross-kernel dependency); block 0 publishes flag.
__global__ __launch_bounds__(256) void k_prep(const void* inp, const void* h,
                        const void* Wq, const void* Wk, const void* Wv,
                        const void* Wi, const void* Wf, const void* Wg, const void* Wo,
                        const void* Wx, const void* Wxg,
                        u16* WB, u16* Wp, u16* UT, u16* xh, int* flag){
  __shared__ float sbuf[8256];          // packw: s[5184]; ut: [64][129]
  __shared__ int cnt[4];
  int tid = threadIdx.x;
  {
    unsigned v = ((const unsigned*)inp)[tid];
    unsigned e = (v >> 7) & 0xFF;
    int is = (e >= 0x70 && e <= 0x88) ? 1 : 0;
    unsigned long long m = __ballot(is);
    if ((tid & 63) == 0) cnt[tid >> 6] = __popcll(m);
  }
  __syncthreads();
  int isbf = (cnt[0]+cnt[1]+cnt[2]+cnt[3] >= 128) ? 1 : 0;
  int b = blockIdx.x;
  if (b == 0 && tid == 0) *flag = isbf;

  if (b < 1792){
    // ---- packw ----
    int ocl = b & 31; int tt = (b >> 5) % 7; int g = b / 224;
    const void* srcs[7] = {Wq, Wk, Wv, Wi, Wf, Wg, Wo};
    const void* src = srcs[tt];
    long long base = (long long)(g*32 + ocl) * 5184;
    for (int i = tid; i < 5184; i += 256) sbuf[i] = ldin(src, base + i, isbf);
    __syncthreads();
    int oc = tt*32 + ocl;
    for (int i = tid; i < 5184; i += 256){
      int kk = i >> 6, ci = i & 63;
      int pos = ((((ci >> 3) ^ (ocl & 7)) << 3) | (ci & 7));
      WB[((size_t)(g*81 + kk)*224 + oc)*64 + pos] = f2b(sbuf[ci*81 + kk]);
    }
  } else if (b < 2112){
    // ---- packp ----
    int el = (b - 1792)*256 + tid;
    if (el < 81920){
      int oc = el / 320, k = el % 320;
      float v = (k < 64) ? ldin(Wx, (long long)oc*64 + k, isbf)
                         : ldin(Wxg, (long long)oc*256 + (k - 64), isbf);
      int win = k >> 6, pos = k & 63;
      int dpos = (win << 6) | ((((pos >> 3) ^ (oc & 7)) << 3)) | (pos & 7);
      Wp[(size_t)oc*320 + dpos] = f2b(v);
    }
  } else {
    // ---- ut ----
    int b2 = b - 2112;
    int qb = b2 % 18; int s = (b2 / 18) % 5; int n = b2 / 90;
    const void* src = (s == 0) ? inp : h;
    long long base = (s == 0) ? (long long)n*64*2304 : ((long long)n*256 + (s-1)*64)*2304;
    for (int i = 0; i < 32; i++){
      int el = tid + i*256; int r = el >> 7, q = el & 127;
      sbuf[r*129 + q] = ldin(src, base + (long long)r*2304 + qb*128 + q, isbf);
    }
    __syncthreads();
    int koff = (s == 0) ? 0 : 64 + (s-1)*64;
    for (int i = 0; i < 4; i++){
      int chunk = tid + i*256;
      int q = chunk >> 3, c8 = chunk & 7;
      bf16x8 v;
      #pragma unroll
      for (int j = 0; j < 8; j++) v[j] = (short)f2b(sbuf[(c8*8 + j)*129 + q]);
      *(bf16x8*)&UT[((size_t)(n*2304 + qb*128 + q))*320 + koff + c8*8] = v;
    }
    if (s > 0){
      for (int i = 0; i < 4; i++){
        int chunk = tid + i*256;
        int q = chunk >> 3, gg = (chunk >> 2) & 1, seg = chunk & 3;
        int g = (s-1)*2 + gg;
        int qg = qb*128 + q; int y = qg / 48, x = qg - y*48;
        bf16x8 v;
        #pragma unroll
        for (int j = 0; j < 8; j++) v[j] = (short)f2b(sbuf[(gg*32 + seg*8 + j)*129 + q]);
        *(bf16x8*)&xh[(((size_t)((n*8+g)*56 + y+4))*56 + (x+4))*64 + 32 + seg*8] = v;
      }
    }
  }
}

// ---------------- proj GEMM: grid 256 = n(4) x ocg(4) x qblk(16) ----------------
// block: [144q][64oc]; 384 thr = 6 waves (wm 3 x 48q, wn 2 x 32oc)
__global__ __launch_bounds__(384) void k_proj(const u16* Wp, const u16* UT, u16* xh){
  int b = blockIdx.x; int qblk = b & 15; int ocg = (b >> 4) & 3; int n = b >> 6;
  int tid = threadIdx.x; int lane = tid & 63; int wid = tid >> 6;
  int wm = wid % 3, wn = wid / 3;
  int quad = lane >> 4, m16 = lane & 15;
  __shared__ __align__(16) u16 lA[144*64];
  __shared__ __align__(16) u16 lB[64*64];
  size_t abase[3];
  #pragma unroll
  for (int r = 0; r < 3; r++){
    int chunk = tid + r*384; int j = chunk >> 3, cs = chunk & 7;
    int cc = cs ^ (j & 7);
    abase[r] = ((size_t)(n*2304 + qblk*144 + j))*320 + cc*8;
  }
  f32x4 acc[3][2];
  #pragma unroll
  for (int a = 0; a < 3; a++)
    #pragma unroll
    for (int c = 0; c < 2; c++) acc[a][c] = (f32x4){0.f,0.f,0.f,0.f};

  for (int kb = 0; kb < 5; kb++){
    __syncthreads();
    #pragma unroll
    for (int r = 0; r < 3; r++)
      gl16(&UT[abase[r] + kb*64], &lA[(tid + r*384)*8]);
    #pragma unroll
    for (int r = 0; r < 2; r++){
      int chunk = tid + r*384;
      if (chunk < 512)
        gl16(&Wp[(size_t)(ocg*64 + (chunk >> 3))*320 + kb*64 + (chunk & 7)*8], &lB[chunk*8]);
    }
    __syncthreads();
    #pragma unroll
    for (int ks = 0; ks < 2; ks++){
      int sw = ((ks*4 + quad) ^ (lane & 7))*8;
      bf16x8 af[3], bfr[2];
      #pragma unroll
      for (int mt = 0; mt < 3; mt++)
        af[mt] = *(const bf16x8*)&lA[(wm*48 + mt*16 + m16)*64 + sw];
      #pragma unroll
      for (int nt = 0; nt < 2; nt++)
        bfr[nt] = *(const bf16x8*)&lB[(wn*32 + nt*16 + m16)*64 + sw];
      #pragma unroll
      for (int mt = 0; mt < 3; mt++)
        #pragma unroll
        for (int nt = 0; nt < 2; nt++)
          acc[mt][nt] = MFMA(af[mt], bfr[nt], acc[mt][nt]);
    }
  }
  #pragma unroll
  for (int mt = 0; mt < 3; mt++)
    #pragma unroll
    for (int nt = 0; nt < 2; nt++)
      #pragma unroll
      for (int r = 0; r < 4; r++){
        int q = qblk*144 + wm*48 + mt*16 + quad*4 + r;
        int oc = ocg*64 + wn*32 + nt*16 + m16;
        int y = q / 48, x = q - y*48;
        int g = oc >> 5, ci = oc & 31;
        xh[(((size_t)((n*8+g)*56 + y+4))*56 + (x+4))*64 + ci] = f2b(acc[mt][nt][r]);
      }
}

// ---------------- fused 7-conv implicit GEMM ----------------
// grid 256 = n(4) x g(8) x qb(8); 768 thr = 12 waves (wm 2 x 112oc, wn 6 x 48sp)
// tile 224 oc x 288 sp. LDS 128KB dbuf. Prefetch issued mid-tap (between ks0/ks1).
__global__ __launch_bounds__(768) void k_conv(const u16* WB, const u16* xh,
                                              u16* Qb, u16* Kt, u16* Vb, u16* Gp){
  extern __shared__ __align__(16) u16 sm[];
  int b = blockIdx.x; int qb = b & 7; int gg = (b >> 3) & 7; int n = b >> 6;
  int tid = threadIdx.x; int lane = tid & 63; int wid = tid >> 6;
  int wm = wid & 1, wn = wid >> 1;
  int quad = lane >> 4, m16 = lane & 15;
  int y0 = qb*6;
  const u16* WBg = WB + (size_t)gg*81*14336;
  const u16* xg  = xh + (size_t)((n*8+gg)*3136)*64;
  int bsrc[3], bdst[3];
  #pragma unroll
  for (int r = 0; r < 3; r++){
    int c = tid + r*768;
    int dy = c / 384, rem = c % 384;
    int col = rem >> 3, cs = rem & 7;
    bsrc[r] = ((y0+dy)*56 + col)*64 + (cs ^ (col & 7))*8;
    bdst[r] = c*8;
  }
  f32x4 acc[7][3];
  #pragma unroll
  for (int a = 0; a < 7; a++)
    #pragma unroll
    for (int c = 0; c < 3; c++) acc[a][c] = (f32x4){0.f,0.f,0.f,0.f};

  {
    u16* A0 = sm;
    u16* B0 = sm + 28672;
    gl16(&WBg[tid*8],       &A0[tid*8]);
    gl16(&WBg[(tid+768)*8], &A0[(tid+768)*8]);
    if (tid < 256) gl16(&WBg[(tid+1536)*8], &A0[(tid+1536)*8]);
    #pragma unroll
    for (int r = 0; r < 3; r++)
      gl16(&xg[bsrc[r]], &B0[bdst[r]]);
  }

  int ky = 0, kx = 0;
  for (int kk = 0; kk < 81; kk++){
    __syncthreads();
    const u16* A = sm + (kk&1)*14336;
    const u16* B = sm + 28672 + (kk&1)*18432;
    // ---- ks0: frags + MFMA (starts immediately after barrier) ----
    {
      bf16x8 af[7], bfr[3];
      #pragma unroll
      for (int mt = 0; mt < 7; mt++){
        int rr = wm*112 + mt*16 + m16;
        af[mt] = *(const bf16x8*)&A[rr*64 + ((quad ^ (rr&7))*8)];
      }
      #pragma unroll
      for (int nt = 0; nt < 3; nt++){
        int sp = wn*48 + nt*16 + m16;
        bfr[nt] = *(const bf16x8*)&B[sp*64 + ((quad ^ (sp&7))*8)];
      }
      #pragma unroll
      for (int mt = 0; mt < 7; mt++)
        #pragma unroll
        for (int nt = 0; nt < 3; nt++)
          acc[mt][nt] = MFMA(af[mt], bfr[nt], acc[mt][nt]);
    }
    // ---- prefetch next tap (mid-tap; ~half a tap of latency cover remains) ----
    if (kk < 80){
      int kx1 = kx + 1, ky1 = ky;
      if (kx1 == 9){ kx1 = 0; ky1++; }
      int nb = (kk+1) & 1;
      u16* An = sm + nb*14336;
      u16* Bn = sm + 28672 + nb*18432;
      const u16* As = WBg + (size_t)(kk+1)*14336;
      gl16(&As[tid*8],       &An[tid*8]);
      gl16(&As[(tid+768)*8], &An[(tid+768)*8]);
      if (tid < 256){ gl16(&As[(tid+1536)*8], &An[(tid+1536)*8]); }
      int koff = (ky1*56 + kx1)*64;
      #pragma unroll
      for (int r = 0; r < 3; r++)
        gl16(&xg[bsrc[r] + koff], &Bn[bdst[r]]);
    }
    // ---- ks1 ----
    {
      bf16x8 af[7], bfr[3];
      #pragma unroll
      for (int mt = 0; mt < 7; mt++){
        int rr = wm*112 + mt*16 + m16;
        af[mt] = *(const bf16x8*)&A[rr*64 + (((4+quad) ^ (rr&7))*8)];
      }
      #pragma unroll
      for (int nt = 0; nt < 3; nt++){
        int sp = wn*48 + nt*16 + m16;
        bfr[nt] = *(const bf16x8*)&B[sp*64 + (((4+quad) ^ (sp&7))*8)];
      }
      #pragma unroll
      for (int mt = 0; mt < 7; mt++)
        #pragma unroll
        for (int nt = 0; nt < 3; nt++)
          acc[mt][nt] = MFMA(af[mt], bfr[nt], acc[mt][nt]);
    }
    kx++; if (kx == 9){ kx = 0; ky++; }
  }
  int y = y0 + wn;
  size_t ng = (size_t)(n*8 + gg);
  #pragma unroll
  for (int mt = 0; mt < 7; mt++){
    int ocb = wm*112 + mt*16 + quad*4;
    #pragma unroll
    for (int nt = 0; nt < 3; nt++){
      int x = nt*16 + m16;
      int q = y*48 + x;
      #pragma unroll
      for (int r = 0; r < 4; r++){
        float v = acc[mt][nt][r];
        int oc = ocb + r;
        int t7 = oc >> 5, ocl = oc & 31;
        if (t7 == 0){
          Qb[(ng*32 + ocl)*2304 + q] = f2b(v);
        } else if (t7 <= 2){
          if ((unsigned)(y-4) < 40u && (unsigned)(x-4) < 40u){
            int d = (y-4)*40 + (x-4);
            if (t7 == 1) Kt[(ng*1600 + d)*32 + ocl] = f2b(v);   // transposed [d][c]
            else         Vb[(ng*32 + ocl)*1600 + d] = f2b(v);
          }
        } else {
          Gp[((ng*4 + (t7-3))*32 + ocl)*2304 + q] = f2b(v);
        }
      }
    }
  }
}

// ---------------- attention (no-max softmax, S^T orientation) + fused gate GEMM ----------------
__global__ __launch_bounds__(256, 3) void k_attn(const u16* Qb, const u16* Kt, const u16* Vb,
                                                 u16* Ga, const void* tau,
                                                 const void* Wai, const void* Waf,
                                                 const void* Wag, const void* Wao,
                                                 const int* flag){
  __shared__ __align__(16) u16 S[22528];
  int b = blockIdx.x; int qb = b % 18; int g = (b / 18) & 7; int n = b / 144;
  int tid = threadIdx.x; int lane = tid & 63; int wid = tid >> 6;
  int quad = lane >> 4, m16 = lane & 15;
  int isbf = *flag;
  size_t ng = (size_t)(n*8 + g);
  const u16* Qg  = Qb + ng*32*2304;
  const u16* Ktg = Kt + ng*1600*32;
  const u16* Vg  = Vb + ng*32*1600;
  float tauv = ldin(tau, g, isbf);
  for (int i = 0; i < 16; i++){
    int el = tid + i*256; int c = el >> 7, q = el & 127;
    S[q*40 + c] = Qg[(size_t)c*2304 + qb*128 + q];
  }
  int kd = tid >> 2, kc = ((tid & 3) ^ ((kd >> 1) & 3))*8;
  int vc = tid >> 3, vd = ((tid & 7) ^ (vc & 7))*8;
  gl16(&Ktg[(size_t)kd*32 + kc], &S[5120 + tid*8]);
  gl16(&Vg[(size_t)vc*1600 + vd], &S[9216 + tid*8]);
  __syncthreads();
  bf16x8 aq[2];
  #pragma unroll
  for (int mtq = 0; mtq < 2; mtq++)
    aq[mtq] = *(const bf16x8*)&S[(wid*32 + mtq*16 + m16)*40 + quad*8];
  __syncthreads();
  {
    const void* Ws[4] = {Wai, Waf, Wag, Wao};
    for (int i = tid; i < 4096; i += 256){
      int gate = i >> 10, oc = (i >> 5) & 31, ci = i & 31;
      S[gate*1280 + oc*40 + ci] = f2b(ldin(Ws[gate], (long long)(g*32 + oc)*32 + ci, isbf));
    }
  }
  f32x4 oacc[3][2];
  #pragma unroll
  for (int a = 0; a < 3; a++)
    #pragma unroll
    for (int c = 0; c < 2; c++) oacc[a][c] = (f32x4){0.f,0.f,0.f,0.f};
  bf16x8 vones;
  #pragma unroll
  for (int j = 0; j < 8; j++) vones[j] = (short)0x3F80;
  u16* myP = &S[13312 + wid*2304];

  for (int dt = 0; dt < 25; dt++){
    __syncthreads();
    const u16* K = &S[5120 + (dt&1)*2048];
    const u16* V = &S[9216 + (dt&1)*2048];
    if (dt < 24){
      gl16(&Ktg[(size_t)((dt+1)*64 + kd)*32 + kc], &S[5120 + (1-(dt&1))*2048 + tid*8]);
      gl16(&Vg[(size_t)vc*1600 + (dt+1)*64 + vd], &S[9216 + (1-(dt&1))*2048 + tid*8]);
    }
    f32x4 sacc[4][2];
    #pragma unroll
    for (int a = 0; a < 4; a++)
      #pragma unroll
      for (int c = 0; c < 2; c++) sacc[a][c] = (f32x4){0.f,0.f,0.f,0.f};
    #pragma unroll
    for (int nt = 0; nt < 4; nt++){
      int d = nt*16 + m16;
      bf16x8 ak = *(const bf16x8*)&K[d*32 + ((quad ^ ((m16 >> 1) & 3))*8)];
      #pragma unroll
      for (int mtq = 0; mtq < 2; mtq++)
        sacc[nt][mtq] = MFMA(ak, aq[mtq], sacc[nt][mtq]);
    }
    #pragma unroll
    for (int nt = 0; nt < 4; nt++)
      #pragma unroll
      for (int mtq = 0; mtq < 2; mtq++){
        unsigned u0 = __float_as_uint(__expf(sacc[nt][mtq][0]*tauv));
        unsigned u1 = __float_as_uint(__expf(sacc[nt][mtq][1]*tauv));
        unsigned u2 = __float_as_uint(__expf(sacc[nt][mtq][2]*tauv));
        unsigned u3 = __float_as_uint(__expf(sacc[nt][mtq][3]*tauv));
        uint2 pk;
        pk.x = (u0 >> 16) | (u1 & 0xFFFF0000u);
        pk.y = (u2 >> 16) | (u3 & 0xFFFF0000u);
        *(uint2*)&myP[(mtq*16 + m16)*72 + nt*16 + quad*4] = pk;
      }
    #pragma unroll
    for (int ks = 0; ks < 2; ks++){
      bf16x8 av[2], bp[2];
      #pragma unroll
      for (int mtc = 0; mtc < 2; mtc++){
        int c = mtc*16 + m16;
        av[mtc] = *(const bf16x8*)&V[c*64 + (((ks*4+quad) ^ (c&7))*8)];
      }
      #pragma unroll
      for (int ntq = 0; ntq < 2; ntq++)
        bp[ntq] = *(const bf16x8*)&myP[(ntq*16 + m16)*72 + ks*32 + quad*8];
      #pragma unroll
      for (int mtc = 0; mtc < 2; mtc++)
        #pragma unroll
        for (int ntq = 0; ntq < 2; ntq++)
          oacc[mtc][ntq] = MFMA(av[mtc], bp[ntq], oacc[mtc][ntq]);
      #pragma unroll
      for (int ntq = 0; ntq < 2; ntq++)
        oacc[2][ntq] = MFMA(vones, bp[ntq], oacc[2][ntq]);
    }
  }
  float linv[2];
  linv[0] = 1.0f / oacc[2][0][0];
  linv[1] = 1.0f / oacc[2][1][0];
  __syncthreads();
  #pragma unroll
  for (int mtc = 0; mtc < 2; mtc++)
    #pragma unroll
    for (int ntq = 0; ntq < 2; ntq++){
      int q = wid*32 + ntq*16 + m16;
      unsigned u0 = __float_as_uint(oacc[mtc][ntq][0] * linv[ntq]);
      unsigned u1 = __float_as_uint(oacc[mtc][ntq][1] * linv[ntq]);
      unsigned u2 = __float_as_uint(oacc[mtc][ntq][2] * linv[ntq]);
      unsigned u3 = __float_as_uint(oacc[mtc][ntq][3] * linv[ntq]);
      uint2 pk;
      pk.x = (u0 >> 16) | (u1 & 0xFFFF0000u);
      pk.y = (u2 >> 16) | (u3 & 0xFFFF0000u);
      *(uint2*)&S[13312 + q*48 + mtc*16 + quad*4] = pk;
    }
  __syncthreads();
  {
    f32x4 gacc[2][8];
    #pragma unroll
    for (int mt = 0; mt < 2; mt++)
      #pragma unroll
      for (int nt = 0; nt < 8; nt++) gacc[mt][nt] = (f32x4){0.f,0.f,0.f,0.f};
    bf16x8 af[2];
    #pragma unroll
    for (int mt = 0; mt < 2; mt++)
      af[mt] = *(const bf16x8*)&S[wid*1280 + (mt*16 + m16)*40 + quad*8];
    #pragma unroll
    for (int nt = 0; nt < 8; nt++){
      bf16x8 bo = *(const bf16x8*)&S[13312 + (nt*16 + m16)*48 + quad*8];
      #pragma unroll
      for (int mt = 0; mt < 2; mt++)
        gacc[mt][nt] = MFMA(af[mt], bo, gacc[mt][nt]);
    }
    size_t gbase = ((ng*4 + wid)*32);
    #pragma unroll
    for (int mt = 0; mt < 2; mt++)
      #pragma unroll
      for (int nt = 0; nt < 8; nt++){
        int q = qb*128 + nt*16 + m16;
        #pragma unroll
        for (int r = 0; r < 4; r++){
          int oc = mt*16 + quad*4 + r;
          Ga[(gbase + oc)*2304 + q] = f2b(gacc[mt][nt][r]);
        }
      }
  }
}

// ---------------- pointwise LSTM finale ----------------
__global__ __launch_bounds__(256) void k_final(const u16* Ga, const u16* Gp,
    const void* bi, const void* bff, const void* bg, const void* bo,
    const void* cprev, void* out, const int* flag){
  int el = (blockIdx.x*256 + threadIdx.x)*8;
  int isbf = *flag;
  int q = el % 2304; int rest = el / 2304;
  int c = rest & 255; int n = rest >> 8;
  int g = c >> 5, oc = c & 31;
  size_t ng = (size_t)(n*8 + g);
  size_t base = ((ng*4)*32 + oc)*2304 + q;
  float b0 = ldin(bi, c, isbf), b1 = ldin(bff, c, isbf);
  float b2 = ldin(bg, c, isbf), b3 = ldin(bo, c, isbf);
  bf16x8 ga0 = *(const bf16x8*)&Ga[base];
  bf16x8 ga1 = *(const bf16x8*)&Ga[base + 73728];
  bf16x8 ga2 = *(const bf16x8*)&Ga[base + 2*73728];
  bf16x8 ga3 = *(const bf16x8*)&Ga[base + 3*73728];
  bf16x8 gp0 = *(const bf16x8*)&Gp[base];
  bf16x8 gp1 = *(const bf16x8*)&Gp[base + 73728];
  bf16x8 gp2 = *(const bf16x8*)&Gp[base + 2*73728];
  bf16x8 gp3 = *(const bf16x8*)&Gp[base + 3*73728];
  float cp[8];
  if (isbf){
    bf16x8 cv = *(const bf16x8*)&((const u16*)cprev)[el];
    #pragma unroll
    for (int j = 0; j < 8; j++) cp[j] = b2f((u16)cv[j]);
  } else {
    f32x4v c0 = *(const f32x4v*)&((const float*)cprev)[el];
    f32x4v c1 = *(const f32x4v*)&((const float*)cprev)[el+4];
    #pragma unroll
    for (int j = 0; j < 4; j++){ cp[j] = c0[j]; cp[4+j] = c1[j]; }
  }
  float hv[8];
  #pragma unroll
  for (int j = 0; j < 8; j++){
    float a0 = b0 + b2f((u16)ga0[j]) + b2f((u16)gp0[j]);
    float a1 = b1 + b2f((u16)ga1[j]) + b2f((u16)gp1[j]);
    float a2 = b2 + b2f((u16)ga2[j]) + b2f((u16)gp2[j]);
    float a3 = b3 + b2f((u16)ga3[j]) + b2f((u16)gp3[j]);
    float gi = sigm(a0), gf = sigm(a1), gv = tanh_f(a2), go = sigm(a3);
    float cn = gf*cp[j] + gi*gv;
    hv[j] = go * tanh_f(cn);
  }
  if (isbf){
    bf16x8 o;
    #pragma unroll
    for (int j = 0; j < 8; j++) o[j] = (short)f2b(hv[j]);
    *(bf16x8*)&((u16*)out)[el] = o;
  } else {
    f32x4v o0, o1;
    #pragma unroll
    for (int j = 0; j < 4; j++){ o0[j] = hv[j]; o1[j] = hv[4+j]; }
    *(f32x4v*)&((float*)out)[el] = o0;
    *(f32x4v*)&((float*)out)[el+4] = o1;
  }
}

extern "C" void kernel_launch(void* const* d_in, const int* in_sizes, int n_in,
                              void* d_out, int out_size, void* d_ws, size_t ws_size,
                              hipStream_t stream){
  const void* inp  = d_in[0];
  const void* h    = d_in[1];
  const void* cpv  = d_in[2];
  const void* Wx   = d_in[3];
  const void* Wxg  = d_in[4];
  const void* tau  = d_in[5];
  const void* Wq   = d_in[6];
  const void* Wk   = d_in[7];
  const void* Wv   = d_in[8];
  const void* Wai  = d_in[9];  const void* Wxi = d_in[10]; const void* bi = d_in[11];
  const void* Waf  = d_in[12]; const void* Wxf = d_in[13]; const void* bff = d_in[14];
  const void* Wag  = d_in[15]; const void* Wxg2 = d_in[16]; const void* bg = d_in[17];
  const void* Wao  = d_in[18]; const void* Wxo = d_in[19]; const void* bo = d_in[20];

  char* ws = (char*)d_ws;
  int*  flag = (int*)(ws + OFF_FLAG);
  u16*  WB = (u16*)(ws + OFF_WB);
  u16*  Wp = (u16*)(ws + OFF_WP);
  u16*  UT = (u16*)(ws + OFF_UT);
  u16*  XH = (u16*)(ws + OFF_XH);
  u16*  Qb = (u16*)(ws + OFF_QB);
  u16*  Kt = (u16*)(ws + OFF_KT);
  u16*  Vb = (u16*)(ws + OFF_VB);
  u16*  Gp = (u16*)(ws + OFF_GP);
  u16*  Ga = (u16*)(ws + OFF_GA);

  (void)hipFuncSetAttribute(reinterpret_cast<const void*>(k_conv),
                            hipFuncAttributeMaxDynamicSharedMemorySize, 131072);

  (void)hipMemsetAsync(XH, 0, SZ_XH, stream);
  k_prep<<<2472, 256, 0, stream>>>(inp, h, Wq, Wk, Wv, Wxi, Wxf, Wxg2, Wxo,
                                   Wx, Wxg, WB, Wp, UT, XH, flag);
  k_proj<<<256, 384, 0, stream>>>(Wp, UT, XH);
  k_conv<<<256, 768, 131072, stream>>>(WB, XH, Qb, Kt, Vb, Gp);
  k_attn<<<576, 256, 0, stream>>>(Qb, Kt, Vb, Ga, tau, Wai, Waf, Wag, Wao, flag);
  k_final<<<1152, 256, 0, stream>>>(Ga, Gp, bi, bff, bg, bo, cpv, d_out, flag);
}